// Round 5
// baseline (221.337 us; speedup 1.0000x reference)
//
#include <hip/hip_runtime.h>

#define EPSF 1e-6f

// dims (fixed for this problem)
#define NB 8
#define LL 4096
#define NHD 8
#define DD 64
#define ROWSTR 512            // H*D
#define NSTR (LL * ROWSTR)    // per-batch stride = 2097152

// workspace float offsets
#define OFF_QSUM 0
#define OFF_KSUM 4096
#define OFF_QNSUM 8192
#define OFF_KNSUM 12288
#define OFF_MX 16384
#define OFF_KV 16448
#define OFF_NCRAW (OFF_KV + 262144)   // 278592
#define OFF_Z (OFF_NCRAW + 262144)    // 540736
#define OFF_KVP (OFF_Z + 64)          // 540800
#define KVP_FLOATS (64 * 16 * 4096)   // 4194304 (16.8 MB of partial kv tiles)

__device__ __forceinline__ float sigf(float x) {
  return 1.0f / (1.0f + __expf(-x));
}

__device__ __forceinline__ float rsum16(float p) {
  p += __shfl_xor(p, 1, 16);
  p += __shfl_xor(p, 2, 16);
  p += __shfl_xor(p, 4, 16);
  p += __shfl_xor(p, 8, 16);
  return p;
}

// ---------------- K1: q_sum / k_sum of sigmoid ----------------
__global__ __launch_bounds__(256) void k_sigsum(const float* __restrict__ q,
                                                const float* __restrict__ k,
                                                float* __restrict__ ws) {
  int bid = blockIdx.x;
  const bool isK = bid >= 4096;
  const float* __restrict__ src = isK ? k : q;
  float* __restrict__ dst = ws + (isK ? OFF_KSUM : OFF_QSUM);
  int id = bid & 4095;
  int nh = id >> 6, chunk = id & 63;
  int n = nh >> 3, h = nh & 7;
  int t = threadIdx.x, tq = t & 15, g = t >> 4;
  const float* base = src + (size_t)n * NSTR + h * DD + tq * 4;
  float4 acc = make_float4(0.f, 0.f, 0.f, 0.f);
  int l0 = chunk * 64 + g;
#pragma unroll
  for (int it = 0; it < 4; ++it) {
    const float4 x = *(const float4*)(base + (size_t)(l0 + it * 16) * ROWSTR);
    acc.x += sigf(x.x); acc.y += sigf(x.y); acc.z += sigf(x.z); acc.w += sigf(x.w);
  }
  __shared__ float4 red[256];
  red[t] = acc;
  __syncthreads();
  for (int s = 128; s >= 16; s >>= 1) {
    if (t < s) {
      float4 o = red[t + s];
      float4 m = red[t];
      m.x += o.x; m.y += o.y; m.z += o.z; m.w += o.w;
      red[t] = m;
    }
    __syncthreads();
  }
  if (t < 16) {
    float4 vv = red[t];
    float* dp = dst + nh * 64 + t * 4;
    atomicAdd(dp + 0, vv.x); atomicAdd(dp + 1, vv.y);
    atomicAdd(dp + 2, vv.z); atomicAdd(dp + 3, vv.w);
  }
}

// ---------------- K2: qn_sum / kn_sum with on-the-fly normalizers ----------------
__global__ __launch_bounds__(256) void k_stage1(const float* __restrict__ q,
                                                const float* __restrict__ k,
                                                float* __restrict__ ws) {
  int bid = blockIdx.x;
  const bool isK = bid >= 4096;
  const float* __restrict__ src = isK ? k : q;
  const float* __restrict__ vsr = ws + (isK ? OFF_QSUM : OFF_KSUM);
  float* __restrict__ dst = ws + (isK ? OFF_KNSUM : OFF_QNSUM);
  int id = bid & 4095;
  int nh = id >> 6, chunk = id & 63;
  int n = nh >> 3, h = nh & 7;
  int t = threadIdx.x, tq = t & 15, g = t >> 4;
  __shared__ float vec[64];
  if (t < 64) vec[t] = vsr[nh * 64 + t] + EPSF;
  __syncthreads();
  const float4 ve = *(const float4*)&vec[tq * 4];
  const float* base = src + (size_t)n * NSTR + h * DD + tq * 4;
  float4 acc = make_float4(0.f, 0.f, 0.f, 0.f);
  int l0 = chunk * 64 + g;
#pragma unroll
  for (int it = 0; it < 4; ++it) {
    const float4 x = *(const float4*)(base + (size_t)(l0 + it * 16) * ROWSTR);
    float4 s;
    s.x = sigf(x.x); s.y = sigf(x.y); s.z = sigf(x.z); s.w = sigf(x.w);
    float p = (s.x + EPSF) * ve.x + (s.y + EPSF) * ve.y +
              (s.z + EPSF) * ve.z + (s.w + EPSF) * ve.w;
    p = rsum16(p);
    float nrm = 1.0f / p;
    acc.x += s.x * nrm; acc.y += s.y * nrm; acc.z += s.z * nrm; acc.w += s.w * nrm;
  }
  __shared__ float4 red[256];
  red[t] = acc;
  __syncthreads();
  for (int s = 128; s >= 16; s >>= 1) {
    if (t < s) {
      float4 o = red[t + s];
      float4 m = red[t];
      m.x += o.x; m.y += o.y; m.z += o.z; m.w += o.w;
      red[t] = m;
    }
    __syncthreads();
  }
  if (t < 16) {
    float4 vv = red[t];
    float* dp = dst + nh * 64 + t * 4;
    atomicAdd(dp + 0, vv.x); atomicAdd(dp + 1, vv.y);
    atomicAdd(dp + 2, vv.z); atomicAdd(dp + 3, vv.w);
  }
}

// ---------------- K3: nc_raw + per-(n,h) max ----------------
__global__ __launch_bounds__(256) void k_ncraw(const float* __restrict__ k,
                                               float* __restrict__ ws) {
  int bid = blockIdx.x;  // 4096
  int nh = bid >> 6, chunk = bid & 63;
  int n = nh >> 3, h = nh & 7;
  int t = threadIdx.x, tq = t & 15, g = t >> 4;
  __shared__ float vec[64];
  if (t < 64) vec[t] = ws[OFF_QNSUM + nh * 64 + t] + EPSF;
  __syncthreads();
  const float4 ve = *(const float4*)&vec[tq * 4];
  const float* base = k + (size_t)n * NSTR + h * DD + tq * 4;
  float* ncp = ws + OFF_NCRAW + nh * LL;
  float mloc = 0.0f;
  int s0 = chunk * 64 + g;
#pragma unroll
  for (int it = 0; it < 4; ++it) {
    int srow = s0 + it * 16;
    const float4 x = *(const float4*)(base + (size_t)srow * ROWSTR);
    float p = (sigf(x.x) + EPSF) * ve.x + (sigf(x.y) + EPSF) * ve.y +
              (sigf(x.z) + EPSF) * ve.z + (sigf(x.w) + EPSF) * ve.w;
    p = rsum16(p);
    if (tq == 0) ncp[srow] = p;
    mloc = fmaxf(mloc, p);
  }
  __shared__ float red[256];
  red[t] = mloc;
  __syncthreads();
  for (int s = 128; s >= 1; s >>= 1) {
    if (t < s) red[t] = fmaxf(red[t], red[t + s]);
    __syncthreads();
  }
  if (t == 0)
    atomicMax((unsigned int*)(ws + OFF_MX) + nh, __float_as_uint(red[0]));
}

// ---------------- K3b: softmax denominator Z per (n,h) ----------------
__global__ __launch_bounds__(256) void k_softz(float* __restrict__ ws) {
  int nh = blockIdx.x, t = threadIdx.x;
  float mx = __uint_as_float(((unsigned int*)(ws + OFF_MX))[nh]);
  const float* nc = ws + OFF_NCRAW + nh * LL;
  float sum = 0.f;
  for (int i = t; i < LL; i += 256) sum += __expf(nc[i] - mx);
  __shared__ float red[256];
  red[t] = sum;
  __syncthreads();
  for (int s = 128; s >= 1; s >>= 1) {
    if (t < s) red[t] += red[t + s];
    __syncthreads();
  }
  if (t == 0) ws[OFF_Z + nh] = red[0];
}

// ---------------- K4: kv[d][e] = sum_s (sig(k)*w)[s,d] * v[s,e] ----------------
// Wave-private LDS tiles: each wave stages its own 16x64 k/v subtile, then
// per row does 4 broadcast ds_read_b128 + 64 FMAs. No barriers in main loop,
// no shuffles. Cross-wave reduce once at the end.
union SmKV2 {
  float tile[4][2][16][72];  // [wave][k/v][row][64+pad]  36.9 KB
  float buf[64 * 65];        // cross-wave reduce          16.6 KB
};

__global__ __launch_bounds__(256, 4) void k_kv(const float* __restrict__ k,
                                               const float* __restrict__ v,
                                               float* __restrict__ ws,
                                               int partial) {
  int bid = blockIdx.x;  // 1024
  int nh = bid >> 4, chunk = bid & 15;
  int n = nh >> 3, h = nh & 7;
  int t = threadIdx.x;
  int w = t >> 6, lane = t & 63;
  float mx = __uint_as_float(((unsigned int*)(ws + OFF_MX))[nh]);
  float scale = (float)LL / ws[OFF_Z + nh];
  const float* kbase = k + (size_t)n * NSTR + h * DD;
  const float* vbase = v + (size_t)n * NSTR + h * DD;
  const float* ncr = ws + OFF_NCRAW + nh * LL;

  __shared__ SmKV2 sm;

  const int s0 = chunk * 256 + w * 64;  // this wave's 64 rows
  const int d8 = (lane >> 3) * 8, e8 = (lane & 7) * 8;
  const int rsub = lane >> 4, tq = lane & 15;

  float acc[8][8];
#pragma unroll
  for (int i = 0; i < 8; ++i)
#pragma unroll
    for (int j = 0; j < 8; ++j) acc[i][j] = 0.f;

  for (int sub = 0; sub < 4; ++sub) {
    const int sbase = s0 + sub * 16;
    // stage 16 rows of sig(k)*wgt and v into this wave's private tile
#pragma unroll
    for (int i = 0; i < 4; ++i) {
      int r = i * 4 + rsub;
      int srow = sbase + r;
      const float4 kx = *(const float4*)(kbase + (size_t)srow * ROWSTR + tq * 4);
      const float4 vx = *(const float4*)(vbase + (size_t)srow * ROWSTR + tq * 4);
      float wgt = __expf(ncr[srow] - mx) * scale;
      *(float4*)&sm.tile[w][0][r][tq * 4] =
          make_float4(sigf(kx.x) * wgt, sigf(kx.y) * wgt, sigf(kx.z) * wgt, sigf(kx.w) * wgt);
      *(float4*)&sm.tile[w][1][r][tq * 4] = vx;
    }
#if __has_builtin(__builtin_amdgcn_wave_barrier)
    __builtin_amdgcn_wave_barrier();  // pin stage-before-read ordering (no-op)
#endif
    // consume: broadcast b128 reads (conflict-free) + FMA
#pragma unroll
    for (int r = 0; r < 16; ++r) {
      float ka[8], va[8];
      *(float4*)&ka[0] = *(const float4*)&sm.tile[w][0][r][d8];
      *(float4*)&ka[4] = *(const float4*)&sm.tile[w][0][r][d8 + 4];
      *(float4*)&va[0] = *(const float4*)&sm.tile[w][1][r][e8];
      *(float4*)&va[4] = *(const float4*)&sm.tile[w][1][r][e8 + 4];
#pragma unroll
      for (int i = 0; i < 8; ++i)
#pragma unroll
        for (int j = 0; j < 8; ++j) acc[i][j] += ka[i] * va[j];
    }
#if __has_builtin(__builtin_amdgcn_wave_barrier)
    __builtin_amdgcn_wave_barrier();  // keep next stage from sliding up
#endif
  }

  // cross-wave reduce, lane-linear layout (stride 65 -> <=2-way, free)
  __syncthreads();  // all waves done with their private tiles (union reuse)
  for (int ww = 0; ww < 4; ++ww) {
    if (w == ww) {
#pragma unroll
      for (int ii = 0; ii < 64; ++ii) {
        int off = lane * 65 + ii;
        float val = acc[ii >> 3][ii & 7];
        if (ww == 0) sm.buf[off] = val;
        else sm.buf[off] += val;
      }
    }
    __syncthreads();
  }

  // write out: thread t handles laneslot l = t&63, 16 values
  int l = t & 63, idx0 = (t >> 6) * 16;
  int dl = (l >> 3) * 8, el = (l & 7) * 8;
  if (partial) {
    float* dst = ws + OFF_KVP + (size_t)bid * 4096;
#pragma unroll
    for (int ii = 0; ii < 16; ++ii) {
      int idx = idx0 + ii;
      int d = dl + (idx >> 3), e = el + (idx & 7);
      dst[d * 64 + e] = sm.buf[l * 65 + idx];
    }
  } else {
    float* kvp = ws + OFF_KV + nh * 4096;
#pragma unroll
    for (int ii = 0; ii < 16; ++ii) {
      int idx = idx0 + ii;
      int d = dl + (idx >> 3), e = el + (idx & 7);
      atomicAdd(&kvp[d * 64 + e], sm.buf[l * 65 + idx]);
    }
  }
}

// ---------------- K4b: reduce 16 partial kv tiles per nh ----------------
__global__ __launch_bounds__(256) void k_kvred(float* __restrict__ ws) {
  int f = blockIdx.x * 256 + threadIdx.x;  // 0..65535 float4 index
  int nh = f >> 10, off = f & 1023;
  const float4* src = (const float4*)(ws + OFF_KVP);
  float4 s = make_float4(0.f, 0.f, 0.f, 0.f);
#pragma unroll
  for (int c = 0; c < 16; ++c) {
    float4 x = src[(size_t)((nh * 16 + c) << 10) + off];
    s.x += x.x; s.y += x.y; s.z += x.z; s.w += x.w;
  }
  ((float4*)(ws + OFF_KV))[f] = s;
}

// ---------------- K5: out = (sig(q) . kv) * nrow * nr ----------------
__global__ __launch_bounds__(256) void k_out(const float* __restrict__ q,
                                             float* __restrict__ out,
                                             const float* __restrict__ ws) {
  int bid = blockIdx.x;  // 2048
  int nh = bid >> 5, chunk = bid & 31;
  int n = nh >> 3, h = nh & 7;
  int t = threadIdx.x, tq = t & 15, g = t >> 4;
  __shared__ float kvs[64][64];
  __shared__ float sq[128][68];   // stride 68: 16B-aligned float4, 2-way banks
  __shared__ float ksv[64], knv[64];
  {
    const float4* kvg = (const float4*)(ws + OFF_KV + (size_t)nh * 4096);
    float4* kvd = (float4*)&kvs[0][0];
#pragma unroll
    for (int i = 0; i < 4; ++i) kvd[i * 256 + t] = kvg[i * 256 + t];
    if (t < 64) {
      ksv[t] = ws[OFF_KSUM + nh * 64 + t] + EPSF;
      knv[t] = ws[OFF_KNSUM + nh * 64 + t] + EPSF;
    }
  }
  __syncthreads();
  const float4 ke = *(const float4*)&ksv[tq * 4];
  const float4 kne = *(const float4*)&knv[tq * 4];
  const float* qbase = q + (size_t)n * NSTR + h * DD + tq * 4;
  float scl[8];
  int l0 = chunk * 128;
#pragma unroll
  for (int rr = 0; rr < 8; ++rr) {
    int row = g + rr * 16;
    const float4 x = *(const float4*)(qbase + (size_t)(l0 + row) * ROWSTR);
    float4 s;
    s.x = sigf(x.x); s.y = sigf(x.y); s.z = sigf(x.z); s.w = sigf(x.w);
    *(float4*)&sq[row][tq * 4] = s;
    float p1 = (s.x + EPSF) * ke.x + (s.y + EPSF) * ke.y +
               (s.z + EPSF) * ke.z + (s.w + EPSF) * ke.w;
    float p2 = (s.x + EPSF) * kne.x + (s.y + EPSF) * kne.y +
               (s.z + EPSF) * kne.z + (s.w + EPSF) * kne.w;
    p1 = rsum16(p1);
    p2 = rsum16(p2);
    scl[rr] = (1.0f / p1) * sigf(p2);  // L/S == 1
  }
  __syncthreads();
  float acc[8][4];
#pragma unroll
  for (int rr = 0; rr < 8; ++rr) {
    acc[rr][0] = 0.f; acc[rr][1] = 0.f; acc[rr][2] = 0.f; acc[rr][3] = 0.f;
  }
  for (int d = 0; d < 64; ++d) {
    const float4 kq = *(const float4*)&kvs[d][tq * 4];
#pragma unroll
    for (int rr = 0; rr < 8; ++rr) {
      float sv = sq[g + rr * 16][d];
      acc[rr][0] += sv * kq.x; acc[rr][1] += sv * kq.y;
      acc[rr][2] += sv * kq.z; acc[rr][3] += sv * kq.w;
    }
  }
  float* obase = out + (size_t)n * NSTR + h * DD + tq * 4;
#pragma unroll
  for (int rr = 0; rr < 8; ++rr) {
    int l = l0 + g + rr * 16;
    float4 o;
    o.x = acc[rr][0] * scl[rr]; o.y = acc[rr][1] * scl[rr];
    o.z = acc[rr][2] * scl[rr]; o.w = acc[rr][3] * scl[rr];
    *(float4*)(obase + (size_t)l * ROWSTR) = o;
  }
}

extern "C" void kernel_launch(void* const* d_in, const int* in_sizes, int n_in,
                              void* d_out, int out_size, void* d_ws, size_t ws_size,
                              hipStream_t stream) {
  const float* q = (const float*)d_in[0];
  const float* k = (const float*)d_in[1];
  const float* v = (const float*)d_in[2];
  float* out = (float*)d_out;
  float* ws = (float*)d_ws;

  // partial-tile path needs ~18.9 MB of ws; fall back to atomics otherwise
  const int partial = (ws_size >= (size_t)(OFF_KVP + KVP_FLOATS) * sizeof(float)) ? 1 : 0;

  // zero accumulators: sums, mx, kv  (nc_raw / Z / kvp are fully overwritten)
  hipMemsetAsync(d_ws, 0, (size_t)OFF_NCRAW * sizeof(float), stream);

  hipLaunchKernelGGL(k_sigsum, dim3(8192), dim3(256), 0, stream, q, k, ws);
  hipLaunchKernelGGL(k_stage1, dim3(8192), dim3(256), 0, stream, q, k, ws);
  hipLaunchKernelGGL(k_ncraw, dim3(4096), dim3(256), 0, stream, k, ws);
  hipLaunchKernelGGL(k_softz, dim3(64), dim3(256), 0, stream, ws);
  hipLaunchKernelGGL(k_kv, dim3(1024), dim3(256), 0, stream, k, v, ws, partial);
  if (partial) hipLaunchKernelGGL(k_kvred, dim3(256), dim3(256), 0, stream, ws);
  hipLaunchKernelGGL(k_out, dim3(2048), dim3(256), 0, stream, q, out, ws);
}

// Round 6
// 217.575 us; speedup vs baseline: 1.0173x; 1.0173x over previous
//
#include <hip/hip_runtime.h>

#define EPSF 1e-6f

// dims (fixed for this problem)
#define NB 8
#define LL 4096
#define NHD 8
#define DD 64
#define ROWSTR 512            // H*D
#define NSTR (LL * ROWSTR)    // per-batch stride = 2097152

// workspace float offsets
#define OFF_QSUM 0
#define OFF_KSUM 4096
#define OFF_QNSUM 8192
#define OFF_KNSUM 12288
#define OFF_Z 16384           // 64 floats (atomicAdd target, inside zeroed span)
#define OFF_KV 16448
#define OFF_NCRAW (OFF_KV + 262144)   // 278592 — holds exp(nc_raw) now
#define OFF_KVP (OFF_NCRAW + 262144)  // 540736
#define KVP_FLOATS (64 * 16 * 4096)   // 4194304 (16.8 MB of partial kv tiles)

__device__ __forceinline__ float sigf(float x) {
  return 1.0f / (1.0f + __expf(-x));
}

__device__ __forceinline__ float rsum16(float p) {
  p += __shfl_xor(p, 1, 16);
  p += __shfl_xor(p, 2, 16);
  p += __shfl_xor(p, 4, 16);
  p += __shfl_xor(p, 8, 16);
  return p;
}

// ---------------- K1: q_sum / k_sum of sigmoid ----------------
__global__ __launch_bounds__(256) void k_sigsum(const float* __restrict__ q,
                                                const float* __restrict__ k,
                                                float* __restrict__ ws) {
  int bid = blockIdx.x;
  const bool isK = bid >= 4096;
  const float* __restrict__ src = isK ? k : q;
  float* __restrict__ dst = ws + (isK ? OFF_KSUM : OFF_QSUM);
  int id = bid & 4095;
  int nh = id >> 6, chunk = id & 63;
  int n = nh >> 3, h = nh & 7;
  int t = threadIdx.x, tq = t & 15, g = t >> 4;
  const float* base = src + (size_t)n * NSTR + h * DD + tq * 4;
  float4 acc = make_float4(0.f, 0.f, 0.f, 0.f);
  int l0 = chunk * 64 + g;
#pragma unroll
  for (int it = 0; it < 4; ++it) {
    const float4 x = *(const float4*)(base + (size_t)(l0 + it * 16) * ROWSTR);
    acc.x += sigf(x.x); acc.y += sigf(x.y); acc.z += sigf(x.z); acc.w += sigf(x.w);
  }
  __shared__ float4 red[256];
  red[t] = acc;
  __syncthreads();
  for (int s = 128; s >= 16; s >>= 1) {
    if (t < s) {
      float4 o = red[t + s];
      float4 m = red[t];
      m.x += o.x; m.y += o.y; m.z += o.z; m.w += o.w;
      red[t] = m;
    }
    __syncthreads();
  }
  if (t < 16) {
    float4 vv = red[t];
    float* dp = dst + nh * 64 + t * 4;
    atomicAdd(dp + 0, vv.x); atomicAdd(dp + 1, vv.y);
    atomicAdd(dp + 2, vv.z); atomicAdd(dp + 3, vv.w);
  }
}

// ---------------- K2: qn_sum / kn_sum with on-the-fly normalizers ----------------
__global__ __launch_bounds__(256) void k_stage1(const float* __restrict__ q,
                                                const float* __restrict__ k,
                                                float* __restrict__ ws) {
  int bid = blockIdx.x;
  const bool isK = bid >= 4096;
  const float* __restrict__ src = isK ? k : q;
  const float* __restrict__ vsr = ws + (isK ? OFF_QSUM : OFF_KSUM);
  float* __restrict__ dst = ws + (isK ? OFF_KNSUM : OFF_QNSUM);
  int id = bid & 4095;
  int nh = id >> 6, chunk = id & 63;
  int n = nh >> 3, h = nh & 7;
  int t = threadIdx.x, tq = t & 15, g = t >> 4;
  __shared__ float vec[64];
  if (t < 64) vec[t] = vsr[nh * 64 + t] + EPSF;
  __syncthreads();
  const float4 ve = *(const float4*)&vec[tq * 4];
  const float* base = src + (size_t)n * NSTR + h * DD + tq * 4;
  float4 acc = make_float4(0.f, 0.f, 0.f, 0.f);
  int l0 = chunk * 64 + g;
#pragma unroll
  for (int it = 0; it < 4; ++it) {
    const float4 x = *(const float4*)(base + (size_t)(l0 + it * 16) * ROWSTR);
    float4 s;
    s.x = sigf(x.x); s.y = sigf(x.y); s.z = sigf(x.z); s.w = sigf(x.w);
    float p = (s.x + EPSF) * ve.x + (s.y + EPSF) * ve.y +
              (s.z + EPSF) * ve.z + (s.w + EPSF) * ve.w;
    p = rsum16(p);
    float nrm = 1.0f / p;
    acc.x += s.x * nrm; acc.y += s.y * nrm; acc.z += s.z * nrm; acc.w += s.w * nrm;
  }
  __shared__ float4 red[256];
  red[t] = acc;
  __syncthreads();
  for (int s = 128; s >= 16; s >>= 1) {
    if (t < s) {
      float4 o = red[t + s];
      float4 m = red[t];
      m.x += o.x; m.y += o.y; m.z += o.z; m.w += o.w;
      red[t] = m;
    }
    __syncthreads();
  }
  if (t < 16) {
    float4 vv = red[t];
    float* dp = dst + nh * 64 + t * 4;
    atomicAdd(dp + 0, vv.x); atomicAdd(dp + 1, vv.y);
    atomicAdd(dp + 2, vv.z); atomicAdd(dp + 3, vv.w);
  }
}

// ---------------- K3: e = exp(nc_raw) + per-(n,h) Z ----------------
// nc_raw = (sig(k)+eps).(qn_sum+eps) is O(1) for these inputs -> no max needed.
__global__ __launch_bounds__(256) void k_ncraw(const float* __restrict__ k,
                                               float* __restrict__ ws) {
  int bid = blockIdx.x;  // 4096
  int nh = bid >> 6, chunk = bid & 63;
  int n = nh >> 3, h = nh & 7;
  int t = threadIdx.x, tq = t & 15, g = t >> 4;
  __shared__ float vec[64];
  if (t < 64) vec[t] = ws[OFF_QNSUM + nh * 64 + t] + EPSF;
  __syncthreads();
  const float4 ve = *(const float4*)&vec[tq * 4];
  const float* base = k + (size_t)n * NSTR + h * DD + tq * 4;
  float* ncp = ws + OFF_NCRAW + nh * LL;
  float zloc = 0.0f;
  int s0 = chunk * 64 + g;
#pragma unroll
  for (int it = 0; it < 4; ++it) {
    int srow = s0 + it * 16;
    const float4 x = *(const float4*)(base + (size_t)srow * ROWSTR);
    float p = (sigf(x.x) + EPSF) * ve.x + (sigf(x.y) + EPSF) * ve.y +
              (sigf(x.z) + EPSF) * ve.z + (sigf(x.w) + EPSF) * ve.w;
    p = rsum16(p);
    float e = __expf(p);
    if (tq == 0) {
      ncp[srow] = e;
      zloc += e;
    }
  }
  __shared__ float red[256];
  red[t] = zloc;
  __syncthreads();
  for (int s = 128; s >= 1; s >>= 1) {
    if (t < s) red[t] += red[t + s];
    __syncthreads();
  }
  if (t == 0) atomicAdd(&ws[OFF_Z + nh], red[0]);
}

// ---------------- K4: kv[d][e] = sum_s (sig(k)*w)[s,d] * v[s,e] ----------------
// Wave-private LDS tiles with bank-swizzled columns + explicit operand
// rotation (software pipeline) in the consume loop.
// Column swizzle: logical word c (0..63) -> phys c + 4*(c>>5); row stride 72.
// Read addrs per 8-lane group then cover all 32 banks (pure broadcast, 0 conflicts).
union SmKV3 {
  float tile[4][2][16][72];  // [wave][k/v][row][swizzled 64+pad]  36.9 KB
  float buf[64 * 65];        // cross-wave reduce                  16.6 KB
};

__global__ __launch_bounds__(256, 4) void k_kv(const float* __restrict__ k,
                                               const float* __restrict__ v,
                                               float* __restrict__ ws,
                                               int partial) {
  int bid = blockIdx.x;  // 1024
  int nh = bid >> 4, chunk = bid & 15;
  int n = nh >> 3, h = nh & 7;
  int t = threadIdx.x;
  int w = t >> 6, lane = t & 63;
  float scale = (float)LL / ws[OFF_Z + nh];
  const float* kbase = k + (size_t)n * NSTR + h * DD;
  const float* vbase = v + (size_t)n * NSTR + h * DD;
  const float* ncr = ws + OFF_NCRAW + nh * LL;  // exp(nc_raw)

  __shared__ SmKV3 sm;

  const int s0 = chunk * 256 + w * 64;  // this wave's 64 rows
  const int rsub = lane >> 4, tq = lane & 15;
  const int cw = tq * 4 + ((tq >> 3) << 2);          // swizzled write col
  const int bd = lane >> 3, be = lane & 7;
  const int cd = bd * 8 + ((bd >> 2) << 2);          // swizzled read col (ka)
  const int ce = be * 8 + ((be >> 2) << 2);          // swizzled read col (va)

  float acc[8][8];
#pragma unroll
  for (int i = 0; i < 8; ++i)
#pragma unroll
    for (int j = 0; j < 8; ++j) acc[i][j] = 0.f;

  const float* tk = &sm.tile[w][0][0][0];
  const float* tv = &sm.tile[w][1][0][0];

  for (int sub = 0; sub < 4; ++sub) {
    const int sbase = s0 + sub * 16;
    // stage 16 rows of sig(k)*wgt and v into this wave's private tile
#pragma unroll
    for (int i = 0; i < 4; ++i) {
      int r = i * 4 + rsub;
      int srow = sbase + r;
      const float4 kx = *(const float4*)(kbase + (size_t)srow * ROWSTR + tq * 4);
      const float4 vx = *(const float4*)(vbase + (size_t)srow * ROWSTR + tq * 4);
      float wgt = ncr[srow] * scale;
      *(float4*)&sm.tile[w][0][r][cw] =
          make_float4(sigf(kx.x) * wgt, sigf(kx.y) * wgt, sigf(kx.z) * wgt, sigf(kx.w) * wgt);
      *(float4*)&sm.tile[w][1][r][cw] = vx;
    }
#if __has_builtin(__builtin_amdgcn_wave_barrier)
    __builtin_amdgcn_wave_barrier();  // pin stage-before-read ordering (no-op)
#endif
    // consume: rotated operands -> next row's reads overlap this row's FMAs
    float4 a0 = *(const float4*)(tk + cd);
    float4 a1 = *(const float4*)(tk + cd + 4);
    float4 b0 = *(const float4*)(tv + ce);
    float4 b1 = *(const float4*)(tv + ce + 4);
#pragma unroll
    for (int r = 0; r < 16; ++r) {
      float4 na0, na1, nb0, nb1;
      if (r < 15) {
        na0 = *(const float4*)(tk + (r + 1) * 72 + cd);
        na1 = *(const float4*)(tk + (r + 1) * 72 + cd + 4);
        nb0 = *(const float4*)(tv + (r + 1) * 72 + ce);
        nb1 = *(const float4*)(tv + (r + 1) * 72 + ce + 4);
      }
      float ka[8] = {a0.x, a0.y, a0.z, a0.w, a1.x, a1.y, a1.z, a1.w};
      float va[8] = {b0.x, b0.y, b0.z, b0.w, b1.x, b1.y, b1.z, b1.w};
#pragma unroll
      for (int i = 0; i < 8; ++i)
#pragma unroll
        for (int j = 0; j < 8; ++j) acc[i][j] += ka[i] * va[j];
      a0 = na0; a1 = na1; b0 = nb0; b1 = nb1;
    }
#if __has_builtin(__builtin_amdgcn_wave_barrier)
    __builtin_amdgcn_wave_barrier();  // keep next stage from sliding up
#endif
  }

  // cross-wave reduce, lane-linear layout (stride 65 -> <=2-way, free)
  __syncthreads();  // all waves done with their private tiles (union reuse)
  for (int ww = 0; ww < 4; ++ww) {
    if (w == ww) {
#pragma unroll
      for (int ii = 0; ii < 64; ++ii) {
        int off = lane * 65 + ii;
        float val = acc[ii >> 3][ii & 7];
        if (ww == 0) sm.buf[off] = val;
        else sm.buf[off] += val;
      }
    }
    __syncthreads();
  }

  // write out: thread t handles laneslot l = t&63, 16 values
  int l = t & 63, idx0 = (t >> 6) * 16;
  int dl = (l >> 3) * 8, el = (l & 7) * 8;
  if (partial) {
    float* dst = ws + OFF_KVP + (size_t)bid * 4096;
#pragma unroll
    for (int ii = 0; ii < 16; ++ii) {
      int idx = idx0 + ii;
      int d = dl + (idx >> 3), e = el + (idx & 7);
      dst[d * 64 + e] = sm.buf[l * 65 + idx];
    }
  } else {
    float* kvp = ws + OFF_KV + nh * 4096;
#pragma unroll
    for (int ii = 0; ii < 16; ++ii) {
      int idx = idx0 + ii;
      int d = dl + (idx >> 3), e = el + (idx & 7);
      atomicAdd(&kvp[d * 64 + e], sm.buf[l * 65 + idx]);
    }
  }
}

// ---------------- K4b: reduce 16 partial kv tiles per nh ----------------
__global__ __launch_bounds__(256) void k_kvred(float* __restrict__ ws) {
  int f = blockIdx.x * 256 + threadIdx.x;  // 0..65535 float4 index
  int nh = f >> 10, off = f & 1023;
  const float4* src = (const float4*)(ws + OFF_KVP);
  float4 s = make_float4(0.f, 0.f, 0.f, 0.f);
#pragma unroll
  for (int c = 0; c < 16; ++c) {
    float4 x = src[(size_t)((nh * 16 + c) << 10) + off];
    s.x += x.x; s.y += x.y; s.z += x.z; s.w += x.w;
  }
  ((float4*)(ws + OFF_KV))[f] = s;
}

// ---------------- K5: out = (sig(q) . kv) * nrow * nr ----------------
__global__ __launch_bounds__(256) void k_out(const float* __restrict__ q,
                                             float* __restrict__ out,
                                             const float* __restrict__ ws) {
  int bid = blockIdx.x;  // 2048
  int nh = bid >> 5, chunk = bid & 31;
  int n = nh >> 3, h = nh & 7;
  int t = threadIdx.x, tq = t & 15, g = t >> 4;
  __shared__ float kvs[64][64];
  __shared__ float sq[128][68];   // stride 68: 16B-aligned float4, 2-way banks
  __shared__ float ksv[64], knv[64];
  {
    const float4* kvg = (const float4*)(ws + OFF_KV + (size_t)nh * 4096);
    float4* kvd = (float4*)&kvs[0][0];
#pragma unroll
    for (int i = 0; i < 4; ++i) kvd[i * 256 + t] = kvg[i * 256 + t];
    if (t < 64) {
      ksv[t] = ws[OFF_KSUM + nh * 64 + t] + EPSF;
      knv[t] = ws[OFF_KNSUM + nh * 64 + t] + EPSF;
    }
  }
  __syncthreads();
  const float4 ke = *(const float4*)&ksv[tq * 4];
  const float4 kne = *(const float4*)&knv[tq * 4];
  const float* qbase = q + (size_t)n * NSTR + h * DD + tq * 4;
  float scl[8];
  int l0 = chunk * 128;
#pragma unroll
  for (int rr = 0; rr < 8; ++rr) {
    int row = g + rr * 16;
    const float4 x = *(const float4*)(qbase + (size_t)(l0 + row) * ROWSTR);
    float4 s;
    s.x = sigf(x.x); s.y = sigf(x.y); s.z = sigf(x.z); s.w = sigf(x.w);
    *(float4*)&sq[row][tq * 4] = s;
    float p1 = (s.x + EPSF) * ke.x + (s.y + EPSF) * ke.y +
               (s.z + EPSF) * ke.z + (s.w + EPSF) * ke.w;
    float p2 = (s.x + EPSF) * kne.x + (s.y + EPSF) * kne.y +
               (s.z + EPSF) * kne.z + (s.w + EPSF) * kne.w;
    p1 = rsum16(p1);
    p2 = rsum16(p2);
    scl[rr] = (1.0f / p1) * sigf(p2);  // L/S == 1
  }
  __syncthreads();
  float acc[8][4];
#pragma unroll
  for (int rr = 0; rr < 8; ++rr) {
    acc[rr][0] = 0.f; acc[rr][1] = 0.f; acc[rr][2] = 0.f; acc[rr][3] = 0.f;
  }
  for (int d = 0; d < 64; ++d) {
    const float4 kq = *(const float4*)&kvs[d][tq * 4];
#pragma unroll
    for (int rr = 0; rr < 8; ++rr) {
      float sv = sq[g + rr * 16][d];
      acc[rr][0] += sv * kq.x; acc[rr][1] += sv * kq.y;
      acc[rr][2] += sv * kq.z; acc[rr][3] += sv * kq.w;
    }
  }
  float* obase = out + (size_t)n * NSTR + h * DD + tq * 4;
#pragma unroll
  for (int rr = 0; rr < 8; ++rr) {
    int l = l0 + g + rr * 16;
    float4 o;
    o.x = acc[rr][0] * scl[rr]; o.y = acc[rr][1] * scl[rr];
    o.z = acc[rr][2] * scl[rr]; o.w = acc[rr][3] * scl[rr];
    *(float4*)(obase + (size_t)l * ROWSTR) = o;
  }
}

extern "C" void kernel_launch(void* const* d_in, const int* in_sizes, int n_in,
                              void* d_out, int out_size, void* d_ws, size_t ws_size,
                              hipStream_t stream) {
  const float* q = (const float*)d_in[0];
  const float* k = (const float*)d_in[1];
  const float* v = (const float*)d_in[2];
  float* out = (float*)d_out;
  float* ws = (float*)d_ws;

  // partial-tile path needs ~18.9 MB of ws; fall back to atomics otherwise
  const int partial = (ws_size >= (size_t)(OFF_KVP + KVP_FLOATS) * sizeof(float)) ? 1 : 0;

  // zero accumulators: sums, Z, kv  (ncraw / kvp are fully overwritten)
  hipMemsetAsync(d_ws, 0, (size_t)OFF_NCRAW * sizeof(float), stream);

  hipLaunchKernelGGL(k_sigsum, dim3(8192), dim3(256), 0, stream, q, k, ws);
  hipLaunchKernelGGL(k_stage1, dim3(8192), dim3(256), 0, stream, q, k, ws);
  hipLaunchKernelGGL(k_ncraw, dim3(4096), dim3(256), 0, stream, k, ws);
  hipLaunchKernelGGL(k_kv, dim3(1024), dim3(256), 0, stream, k, v, ws, partial);
  if (partial) hipLaunchKernelGGL(k_kvred, dim3(256), dim3(256), 0, stream, ws);
  hipLaunchKernelGGL(k_out, dim3(2048), dim3(256), 0, stream, q, out, ws);
}

// Round 7
// 157.445 us; speedup vs baseline: 1.4058x; 1.3819x over previous
//
#include <hip/hip_runtime.h>

#define EPSF 1e-6f

// dims (fixed for this problem)
#define NB 8
#define LL 4096
#define NHD 8
#define DD 64
#define ROWSTR 512            // H*D
#define NSTR (LL * ROWSTR)    // per-batch stride = 2097152

// workspace float offsets
#define OFF_QSUM 0
#define OFF_KSUM 4096
#define OFF_QNSUM 8192
#define OFF_KNSUM 12288
#define OFF_Z 16384           // 64 floats (atomicAdd target, inside zeroed span)
#define OFF_KV 16448
#define OFF_KVP (OFF_KV + 262144)     // 278592: 64 nh x 8 chunks x 4096 partials
#define KVP_FLOATS (64 * 8 * 4096)    // 2097152

typedef __attribute__((ext_vector_type(8))) short short8v;  // 8 bf16 (4 VGPRs)
typedef __attribute__((ext_vector_type(4))) float f32x4;

__device__ __forceinline__ float sigf(float x) {
  return 1.0f / (1.0f + __expf(-x));
}

__device__ __forceinline__ float rsum16(float p) {
  p += __shfl_xor(p, 1, 16);
  p += __shfl_xor(p, 2, 16);
  p += __shfl_xor(p, 4, 16);
  p += __shfl_xor(p, 8, 16);
  return p;
}

__device__ __forceinline__ float rsum8(float p) {
  p += __shfl_xor(p, 1, 8);
  p += __shfl_xor(p, 2, 8);
  p += __shfl_xor(p, 4, 8);
  return p;
}

// split fp32 -> bf16 hi + bf16 lo (RNE both); hi+lo reconstructs to ~2^-18 rel
__device__ __forceinline__ void bsplit(float x, unsigned short& h, unsigned short& l) {
  unsigned int u = __float_as_uint(x);
  unsigned int hr = (u + 0x7FFFu + ((u >> 16) & 1u)) >> 16;
  h = (unsigned short)hr;
  float hf = __uint_as_float(hr << 16);
  float r = x - hf;
  unsigned int u2 = __float_as_uint(r);
  l = (unsigned short)((u2 + 0x7FFFu + ((u2 >> 16) & 1u)) >> 16);
}

// ---------------- K1: q_sum / k_sum of sigmoid ----------------
__global__ __launch_bounds__(256) void k_sigsum(const float* __restrict__ q,
                                                const float* __restrict__ k,
                                                float* __restrict__ ws) {
  int bid = blockIdx.x;
  const bool isK = bid >= 4096;
  const float* __restrict__ src = isK ? k : q;
  float* __restrict__ dst = ws + (isK ? OFF_KSUM : OFF_QSUM);
  int id = bid & 4095;
  int nh = id >> 6, chunk = id & 63;
  int n = nh >> 3, h = nh & 7;
  int t = threadIdx.x, tq = t & 15, g = t >> 4;
  const float* base = src + (size_t)n * NSTR + h * DD + tq * 4;
  float4 acc = make_float4(0.f, 0.f, 0.f, 0.f);
  int l0 = chunk * 64 + g;
#pragma unroll
  for (int it = 0; it < 4; ++it) {
    const float4 x = *(const float4*)(base + (size_t)(l0 + it * 16) * ROWSTR);
    acc.x += sigf(x.x); acc.y += sigf(x.y); acc.z += sigf(x.z); acc.w += sigf(x.w);
  }
  __shared__ float4 red[256];
  red[t] = acc;
  __syncthreads();
  for (int s = 128; s >= 16; s >>= 1) {
    if (t < s) {
      float4 o = red[t + s];
      float4 m = red[t];
      m.x += o.x; m.y += o.y; m.z += o.z; m.w += o.w;
      red[t] = m;
    }
    __syncthreads();
  }
  if (t < 16) {
    float4 vv = red[t];
    float* dp = dst + nh * 64 + t * 4;
    atomicAdd(dp + 0, vv.x); atomicAdd(dp + 1, vv.y);
    atomicAdd(dp + 2, vv.z); atomicAdd(dp + 3, vv.w);
  }
}

// ---------------- K2: qn_sum / kn_sum with on-the-fly normalizers ----------------
__global__ __launch_bounds__(256) void k_stage1(const float* __restrict__ q,
                                                const float* __restrict__ k,
                                                float* __restrict__ ws) {
  int bid = blockIdx.x;
  const bool isK = bid >= 4096;
  const float* __restrict__ src = isK ? k : q;
  const float* __restrict__ vsr = ws + (isK ? OFF_QSUM : OFF_KSUM);
  float* __restrict__ dst = ws + (isK ? OFF_KNSUM : OFF_QNSUM);
  int id = bid & 4095;
  int nh = id >> 6, chunk = id & 63;
  int n = nh >> 3, h = nh & 7;
  int t = threadIdx.x, tq = t & 15, g = t >> 4;
  __shared__ float vec[64];
  if (t < 64) vec[t] = vsr[nh * 64 + t] + EPSF;
  __syncthreads();
  const float4 ve = *(const float4*)&vec[tq * 4];
  const float* base = src + (size_t)n * NSTR + h * DD + tq * 4;
  float4 acc = make_float4(0.f, 0.f, 0.f, 0.f);
  int l0 = chunk * 64 + g;
#pragma unroll
  for (int it = 0; it < 4; ++it) {
    const float4 x = *(const float4*)(base + (size_t)(l0 + it * 16) * ROWSTR);
    float4 s;
    s.x = sigf(x.x); s.y = sigf(x.y); s.z = sigf(x.z); s.w = sigf(x.w);
    float p = (s.x + EPSF) * ve.x + (s.y + EPSF) * ve.y +
              (s.z + EPSF) * ve.z + (s.w + EPSF) * ve.w;
    p = rsum16(p);
    float nrm = 1.0f / p;
    acc.x += s.x * nrm; acc.y += s.y * nrm; acc.z += s.z * nrm; acc.w += s.w * nrm;
  }
  __shared__ float4 red[256];
  red[t] = acc;
  __syncthreads();
  for (int s = 128; s >= 16; s >>= 1) {
    if (t < s) {
      float4 o = red[t + s];
      float4 m = red[t];
      m.x += o.x; m.y += o.y; m.z += o.z; m.w += o.w;
      red[t] = m;
    }
    __syncthreads();
  }
  if (t < 16) {
    float4 vv = red[t];
    float* dp = dst + nh * 64 + t * 4;
    atomicAdd(dp + 0, vv.x); atomicAdd(dp + 1, vv.y);
    atomicAdd(dp + 2, vv.z); atomicAdd(dp + 3, vv.w);
  }
}

// ---------------- K4: kv = khat^T v via MFMA (ncraw fused in) ----------------
// Per block: nh = bid>>3, 512 rows of s. 512 threads = 8 waves.
// Staging: each thread loads 2 float4 of k + 2 of v for one row, computes
// sigma, nc-dot (rsum8), wgt = exp(nc) (unnormalized; S/Z applied in k_kvred),
// splits khat = sig(k)*wgt and v into bf16 hi/lo, stores TRANSPOSED tiles
// kt[d][s], vt[e][s] (stride 72 bf16: 16B-aligned frags, balanced banks).
// Consume: wave w -> d-block (w>>1), e-tiles {2*(w&1), 2*(w&1)+1}.
// 3-term split product: hi*hi + hi*lo + lo*hi (lo*lo dropped, ~2^-18 rel).
__global__ __launch_bounds__(512, 4) void k_kv(const float* __restrict__ k,
                                               const float* __restrict__ v,
                                               float* __restrict__ ws) {
  const int bid = blockIdx.x;  // 512
  const int nh = bid >> 3, chunk = bid & 7;
  const int n = nh >> 3, h = nh & 7;
  const int t = threadIdx.x;

  __shared__ unsigned short kt_hi[64][72], kt_lo[64][72];
  __shared__ unsigned short vt_hi[64][72], vt_lo[64][72];
  __shared__ float zred[512];

  const float* kbase = k + (size_t)n * NSTR + h * DD;
  const float* vbase = v + (size_t)n * NSTR + h * DD;

  // ---- staging ids: thread handles local row (t>>3), col groups c0/c1
  const int srow_l = t >> 3;       // 0..63
  const int tq = t & 7;            // 0..7
  const int c0 = tq * 4, c1 = 32 + tq * 4;
  const int s0 = chunk * 512;

  // qn_sum (+EPS) for this lane's 8 columns
  const float* qnp = ws + OFF_QNSUM + nh * 64;
  float4 qa = *(const float4*)(qnp + c0);
  float4 qb = *(const float4*)(qnp + c1);
  qa.x += EPSF; qa.y += EPSF; qa.z += EPSF; qa.w += EPSF;
  qb.x += EPSF; qb.y += EPSF; qb.z += EPSF; qb.w += EPSF;

  // ---- consume ids
  const int w = t >> 6, lane = t & 63;
  const int dblk = w >> 1, ep = w & 1;
  const int m = lane & 15, grp = lane >> 4;
  const int arow = 16 * dblk + m;
  const int brow0 = 16 * (2 * ep) + m;
  const int brow1 = 16 * (2 * ep + 1) + m;

  f32x4 acc0 = {0.f, 0.f, 0.f, 0.f};
  f32x4 acc1 = {0.f, 0.f, 0.f, 0.f};
  float zloc = 0.f;

  // prologue: load subtile 0
  const float* krow = kbase + (size_t)(s0 + srow_l) * ROWSTR;
  const float* vrow = vbase + (size_t)(s0 + srow_l) * ROWSTR;
  float4 kA = *(const float4*)(krow + c0);
  float4 kB = *(const float4*)(krow + c1);
  float4 vA = *(const float4*)(vrow + c0);
  float4 vB = *(const float4*)(vrow + c1);

  for (int sub = 0; sub < 8; ++sub) {
    float4 kAn, kBn, vAn, vBn;
    if (sub < 7) {
      const float* krn = kbase + (size_t)(s0 + (sub + 1) * 64 + srow_l) * ROWSTR;
      const float* vrn = vbase + (size_t)(s0 + (sub + 1) * 64 + srow_l) * ROWSTR;
      kAn = *(const float4*)(krn + c0);
      kBn = *(const float4*)(krn + c1);
      vAn = *(const float4*)(vrn + c0);
      vBn = *(const float4*)(vrn + c1);
    }
    // sigma
    float sk[8];
    sk[0] = sigf(kA.x); sk[1] = sigf(kA.y); sk[2] = sigf(kA.z); sk[3] = sigf(kA.w);
    sk[4] = sigf(kB.x); sk[5] = sigf(kB.y); sk[6] = sigf(kB.z); sk[7] = sigf(kB.w);
    // nc dot over this row (8 lanes x 8 cols)
    float p = (sk[0] + EPSF) * qa.x + (sk[1] + EPSF) * qa.y +
              (sk[2] + EPSF) * qa.z + (sk[3] + EPSF) * qa.w +
              (sk[4] + EPSF) * qb.x + (sk[5] + EPSF) * qb.y +
              (sk[6] + EPSF) * qb.z + (sk[7] + EPSF) * qb.w;
    p = rsum8(p);
    float wgt = __expf(p);
    if (tq == 0) zloc += wgt;
    // split khat and v, store transposed
    float vv[8] = {vA.x, vA.y, vA.z, vA.w, vB.x, vB.y, vB.z, vB.w};
#pragma unroll
    for (int i = 0; i < 8; ++i) {
      int d = (i < 4) ? (c0 + i) : (c1 + i - 4);
      unsigned short hh, ll;
      bsplit(sk[i] * wgt, hh, ll);
      kt_hi[d][srow_l] = hh; kt_lo[d][srow_l] = ll;
      bsplit(vv[i], hh, ll);
      vt_hi[d][srow_l] = hh; vt_lo[d][srow_l] = ll;
    }
    __syncthreads();
    // consume: 2 k-steps of 32
#pragma unroll
    for (int ks = 0; ks < 2; ++ks) {
      const int sb = ks * 32 + 8 * grp;
      short8v Ah = *(const short8v*)&kt_hi[arow][sb];
      short8v Al = *(const short8v*)&kt_lo[arow][sb];
      short8v B0h = *(const short8v*)&vt_hi[brow0][sb];
      short8v B0l = *(const short8v*)&vt_lo[brow0][sb];
      short8v B1h = *(const short8v*)&vt_hi[brow1][sb];
      short8v B1l = *(const short8v*)&vt_lo[brow1][sb];
      acc0 = __builtin_amdgcn_mfma_f32_16x16x32_bf16(Ah, B0h, acc0, 0, 0, 0);
      acc0 = __builtin_amdgcn_mfma_f32_16x16x32_bf16(Ah, B0l, acc0, 0, 0, 0);
      acc0 = __builtin_amdgcn_mfma_f32_16x16x32_bf16(Al, B0h, acc0, 0, 0, 0);
      acc1 = __builtin_amdgcn_mfma_f32_16x16x32_bf16(Ah, B1h, acc1, 0, 0, 0);
      acc1 = __builtin_amdgcn_mfma_f32_16x16x32_bf16(Ah, B1l, acc1, 0, 0, 0);
      acc1 = __builtin_amdgcn_mfma_f32_16x16x32_bf16(Al, B1h, acc1, 0, 0, 0);
    }
    __syncthreads();
    kA = kAn; kB = kBn; vA = vAn; vB = vBn;
  }

  // write partial tile: D row = 16*dblk + 4*grp + reg, col = 16*tile + m
  float* dst = ws + OFF_KVP + (size_t)bid * 4096;
  const int drow = 16 * dblk + 4 * grp;
#pragma unroll
  for (int r = 0; r < 4; ++r) {
    dst[(drow + r) * 64 + brow0] = acc0[r];
    dst[(drow + r) * 64 + brow1] = acc1[r];
  }

  // Z reduction
  zred[t] = zloc;
  __syncthreads();
  for (int s = 256; s >= 1; s >>= 1) {
    if (t < s) zred[t] += zred[t + s];
    __syncthreads();
  }
  if (t == 0) atomicAdd(&ws[OFF_Z + nh], zred[0]);
}

// ---------------- K4b: reduce 8 partial kv tiles per nh, apply S/Z ----------------
__global__ __launch_bounds__(256) void k_kvred(float* __restrict__ ws) {
  int f = blockIdx.x * 256 + threadIdx.x;  // 0..65535 float4 index
  int nh = f >> 10, off = f & 1023;
  float scale = (float)LL / ws[OFF_Z + nh];
  const float4* src = (const float4*)(ws + OFF_KVP);
  float4 s = make_float4(0.f, 0.f, 0.f, 0.f);
#pragma unroll
  for (int c = 0; c < 8; ++c) {
    float4 x = src[(size_t)((nh * 8 + c) << 10) + off];
    s.x += x.x; s.y += x.y; s.z += x.z; s.w += x.w;
  }
  s.x *= scale; s.y *= scale; s.z *= scale; s.w *= scale;
  ((float4*)(ws + OFF_KV))[f] = s;
}

// ---------------- K5: out = (sig(q) . kv) * nrow * nr ----------------
__global__ __launch_bounds__(256) void k_out(const float* __restrict__ q,
                                             float* __restrict__ out,
                                             const float* __restrict__ ws) {
  int bid = blockIdx.x;  // 2048
  int nh = bid >> 5, chunk = bid & 31;
  int n = nh >> 3, h = nh & 7;
  int t = threadIdx.x, tq = t & 15, g = t >> 4;
  __shared__ float kvs[64][64];
  __shared__ float sq[128][68];   // stride 68: 16B-aligned float4, 2-way banks
  __shared__ float ksv[64], knv[64];
  {
    const float4* kvg = (const float4*)(ws + OFF_KV + (size_t)nh * 4096);
    float4* kvd = (float4*)&kvs[0][0];
#pragma unroll
    for (int i = 0; i < 4; ++i) kvd[i * 256 + t] = kvg[i * 256 + t];
    if (t < 64) {
      ksv[t] = ws[OFF_KSUM + nh * 64 + t] + EPSF;
      knv[t] = ws[OFF_KNSUM + nh * 64 + t] + EPSF;
    }
  }
  __syncthreads();
  const float4 ke = *(const float4*)&ksv[tq * 4];
  const float4 kne = *(const float4*)&knv[tq * 4];
  const float* qbase = q + (size_t)n * NSTR + h * DD + tq * 4;
  float scl[8];
  int l0 = chunk * 128;
#pragma unroll
  for (int rr = 0; rr < 8; ++rr) {
    int row = g + rr * 16;
    const float4 x = *(const float4*)(qbase + (size_t)(l0 + row) * ROWSTR);
    float4 s;
    s.x = sigf(x.x); s.y = sigf(x.y); s.z = sigf(x.z); s.w = sigf(x.w);
    *(float4*)&sq[row][tq * 4] = s;
    float p1 = (s.x + EPSF) * ke.x + (s.y + EPSF) * ke.y +
               (s.z + EPSF) * ke.z + (s.w + EPSF) * ke.w;
    float p2 = (s.x + EPSF) * kne.x + (s.y + EPSF) * kne.y +
               (s.z + EPSF) * kne.z + (s.w + EPSF) * kne.w;
    p1 = rsum16(p1);
    p2 = rsum16(p2);
    scl[rr] = (1.0f / p1) * sigf(p2);  // L/S == 1
  }
  __syncthreads();
  float acc[8][4];
#pragma unroll
  for (int rr = 0; rr < 8; ++rr) {
    acc[rr][0] = 0.f; acc[rr][1] = 0.f; acc[rr][2] = 0.f; acc[rr][3] = 0.f;
  }
  for (int d = 0; d < 64; ++d) {
    const float4 kq = *(const float4*)&kvs[d][tq * 4];
#pragma unroll
    for (int rr = 0; rr < 8; ++rr) {
      float sv = sq[g + rr * 16][d];
      acc[rr][0] += sv * kq.x; acc[rr][1] += sv * kq.y;
      acc[rr][2] += sv * kq.z; acc[rr][3] += sv * kq.w;
    }
  }
  float* obase = out + (size_t)n * NSTR + h * DD + tq * 4;
#pragma unroll
  for (int rr = 0; rr < 8; ++rr) {
    int l = l0 + g + rr * 16;
    float4 o;
    o.x = acc[rr][0] * scl[rr]; o.y = acc[rr][1] * scl[rr];
    o.z = acc[rr][2] * scl[rr]; o.w = acc[rr][3] * scl[rr];
    *(float4*)(obase + (size_t)l * ROWSTR) = o;
  }
}

extern "C" void kernel_launch(void* const* d_in, const int* in_sizes, int n_in,
                              void* d_out, int out_size, void* d_ws, size_t ws_size,
                              hipStream_t stream) {
  const float* q = (const float*)d_in[0];
  const float* k = (const float*)d_in[1];
  const float* v = (const float*)d_in[2];
  float* out = (float*)d_out;
  float* ws = (float*)d_ws;

  // zero accumulators: sums + Z  (kv/kvp fully overwritten each launch)
  hipMemsetAsync(d_ws, 0, (size_t)OFF_KV * sizeof(float), stream);

  hipLaunchKernelGGL(k_sigsum, dim3(8192), dim3(256), 0, stream, q, k, ws);
  hipLaunchKernelGGL(k_stage1, dim3(8192), dim3(256), 0, stream, q, k, ws);
  hipLaunchKernelGGL(k_kv, dim3(512), dim3(512), 0, stream, k, v, ws);
  hipLaunchKernelGGL(k_kvred, dim3(256), dim3(256), 0, stream, ws);
  hipLaunchKernelGGL(k_out, dim3(2048), dim3(256), 0, stream, q, out, ws);
}

// Round 8
// 145.434 us; speedup vs baseline: 1.5219x; 1.0826x over previous
//
#include <hip/hip_runtime.h>

#define EPSF 1e-6f

// dims (fixed for this problem)
#define NB 8
#define LL 4096
#define NHD 8
#define DD 64
#define ROWSTR 512            // H*D
#define NSTR (LL * ROWSTR)    // per-batch stride = 2097152

// workspace float offsets
#define OFF_QSUM 0
#define OFF_KSUM 4096
#define OFF_QNSUM 8192
#define OFF_KNSUM 12288
#define OFF_Z 16384           // 64 floats (atomicAdd target, inside zeroed span)
#define OFF_KV 16448
#define OFF_KVP (OFF_KV + 262144)     // 278592: 64 nh x 8 chunks x 4096 partials
#define KVP_FLOATS (64 * 8 * 4096)    // 2097152

typedef __attribute__((ext_vector_type(8))) short short8v;  // 8 bf16 (4 VGPRs)
typedef __attribute__((ext_vector_type(4))) float f32x4;

__device__ __forceinline__ float sigf(float x) {
  return 1.0f / (1.0f + __expf(-x));
}

__device__ __forceinline__ float rsum16(float p) {
  p += __shfl_xor(p, 1, 16);
  p += __shfl_xor(p, 2, 16);
  p += __shfl_xor(p, 4, 16);
  p += __shfl_xor(p, 8, 16);
  return p;
}

__device__ __forceinline__ float rsum8(float p) {
  p += __shfl_xor(p, 1, 8);
  p += __shfl_xor(p, 2, 8);
  p += __shfl_xor(p, 4, 8);
  return p;
}

// split fp32 -> bf16 hi + bf16 lo (RNE both); hi+lo reconstructs to ~2^-18 rel
__device__ __forceinline__ void bsplit(float x, unsigned short& h, unsigned short& l) {
  unsigned int u = __float_as_uint(x);
  unsigned int hr = (u + 0x7FFFu + ((u >> 16) & 1u)) >> 16;
  h = (unsigned short)hr;
  float hf = __uint_as_float(hr << 16);
  float r = x - hf;
  unsigned int u2 = __float_as_uint(r);
  l = (unsigned short)((u2 + 0x7FFFu + ((u2 >> 16) & 1u)) >> 16);
}

// ---------------- K1: q_sum / k_sum of sigmoid (contiguous-row layout) ----------------
// Block covers 64 full rows (all 8 heads): 128 KB contiguous. Thread t owns
// fixed columns (t*4)&511 across rows; per-head sums fold in LDS, then atomics.
__global__ __launch_bounds__(256) void k_sigsum(const float* __restrict__ q,
                                                const float* __restrict__ k,
                                                float* __restrict__ ws) {
  int bid = blockIdx.x;  // 1024
  const bool isK = bid >= 512;
  const float* __restrict__ src = isK ? k : q;
  float* __restrict__ dst = ws + (isK ? OFF_KSUM : OFF_QSUM);
  int id = bid & 511;
  int n = id >> 6, chunk = id & 63;
  int t = threadIdx.x;
  const float* base = src + (size_t)n * NSTR + (size_t)chunk * 64 * ROWSTR + t * 4;
  float4 acc = make_float4(0.f, 0.f, 0.f, 0.f);
#pragma unroll 4
  for (int it = 0; it < 32; ++it) {
    const float4 x = *(const float4*)(base + (size_t)it * 1024);
    acc.x += sigf(x.x); acc.y += sigf(x.y); acc.z += sigf(x.z); acc.w += sigf(x.w);
  }
  __shared__ float red[512];
  if (t < 128) {
    red[t * 4 + 0] = acc.x; red[t * 4 + 1] = acc.y;
    red[t * 4 + 2] = acc.z; red[t * 4 + 3] = acc.w;
  }
  __syncthreads();
  if (t >= 128) {
    int c = (t - 128) * 4;
    red[c + 0] += acc.x; red[c + 1] += acc.y;
    red[c + 2] += acc.z; red[c + 3] += acc.w;
  }
  __syncthreads();
  if (t < 128) {
    float* dp = dst + n * 512 + t * 4;  // [n][h][64] contiguous = n*512 + col
    atomicAdd(dp + 0, red[t * 4 + 0]); atomicAdd(dp + 1, red[t * 4 + 1]);
    atomicAdd(dp + 2, red[t * 4 + 2]); atomicAdd(dp + 3, red[t * 4 + 3]);
  }
}

// ---------------- K2: qn_sum / kn_sum (contiguous-row layout) ----------------
// Same mapping; per-row-per-head normalizer dot reduces across the 16 lanes
// of each head group (lane groups align with heads: h = (t>>4)&7).
__global__ __launch_bounds__(256) void k_stage1(const float* __restrict__ q,
                                                const float* __restrict__ k,
                                                float* __restrict__ ws) {
  int bid = blockIdx.x;  // 1024
  const bool isK = bid >= 512;
  const float* __restrict__ src = isK ? k : q;
  const float* __restrict__ vsr = ws + (isK ? OFF_QSUM : OFF_KSUM);
  float* __restrict__ dst = ws + (isK ? OFF_KNSUM : OFF_QNSUM);
  int id = bid & 511;
  int n = id >> 6, chunk = id & 63;
  int t = threadIdx.x;
  int col = (t * 4) & 511;  // fixed column quad; h = col>>6
  __shared__ float vec[512];
  if (t < 128) {
    vec[t * 4 + 0] = vsr[n * 512 + t * 4 + 0] + EPSF;
    vec[t * 4 + 1] = vsr[n * 512 + t * 4 + 1] + EPSF;
    vec[t * 4 + 2] = vsr[n * 512 + t * 4 + 2] + EPSF;
    vec[t * 4 + 3] = vsr[n * 512 + t * 4 + 3] + EPSF;
  }
  __syncthreads();
  const float4 ve = *(const float4*)&vec[col];
  const float* base = src + (size_t)n * NSTR + (size_t)chunk * 64 * ROWSTR + t * 4;
  float4 acc = make_float4(0.f, 0.f, 0.f, 0.f);
#pragma unroll 4
  for (int it = 0; it < 32; ++it) {
    const float4 x = *(const float4*)(base + (size_t)it * 1024);
    float4 s;
    s.x = sigf(x.x); s.y = sigf(x.y); s.z = sigf(x.z); s.w = sigf(x.w);
    float p = (s.x + EPSF) * ve.x + (s.y + EPSF) * ve.y +
              (s.z + EPSF) * ve.z + (s.w + EPSF) * ve.w;
    p = rsum16(p);  // 16 lanes of this head in this row
    float nrm = 1.0f / p;
    acc.x += s.x * nrm; acc.y += s.y * nrm; acc.z += s.z * nrm; acc.w += s.w * nrm;
  }
  __shared__ float red[512];
  if (t < 128) {
    red[t * 4 + 0] = acc.x; red[t * 4 + 1] = acc.y;
    red[t * 4 + 2] = acc.z; red[t * 4 + 3] = acc.w;
  }
  __syncthreads();
  if (t >= 128) {
    int c = (t - 128) * 4;
    red[c + 0] += acc.x; red[c + 1] += acc.y;
    red[c + 2] += acc.z; red[c + 3] += acc.w;
  }
  __syncthreads();
  if (t < 128) {
    float* dp = dst + n * 512 + t * 4;
    atomicAdd(dp + 0, red[t * 4 + 0]); atomicAdd(dp + 1, red[t * 4 + 1]);
    atomicAdd(dp + 2, red[t * 4 + 2]); atomicAdd(dp + 3, red[t * 4 + 3]);
  }
}

// ---------------- K4: kv = khat^T v via MFMA (ncraw fused in) ----------------
__global__ __launch_bounds__(512, 4) void k_kv(const float* __restrict__ k,
                                               const float* __restrict__ v,
                                               float* __restrict__ ws) {
  const int bid = blockIdx.x;  // 512
  const int nh = bid >> 3, chunk = bid & 7;
  const int n = nh >> 3, h = nh & 7;
  const int t = threadIdx.x;

  __shared__ unsigned short kt_hi[64][72], kt_lo[64][72];
  __shared__ unsigned short vt_hi[64][72], vt_lo[64][72];
  __shared__ float zred[512];

  const float* kbase = k + (size_t)n * NSTR + h * DD;
  const float* vbase = v + (size_t)n * NSTR + h * DD;

  const int srow_l = t >> 3;       // 0..63
  const int tq = t & 7;            // 0..7
  const int c0 = tq * 4, c1 = 32 + tq * 4;
  const int s0 = chunk * 512;

  const float* qnp = ws + OFF_QNSUM + nh * 64;
  float4 qa = *(const float4*)(qnp + c0);
  float4 qb = *(const float4*)(qnp + c1);
  qa.x += EPSF; qa.y += EPSF; qa.z += EPSF; qa.w += EPSF;
  qb.x += EPSF; qb.y += EPSF; qb.z += EPSF; qb.w += EPSF;

  const int w = t >> 6, lane = t & 63;
  const int dblk = w >> 1, ep = w & 1;
  const int m = lane & 15, grp = lane >> 4;
  const int arow = 16 * dblk + m;
  const int brow0 = 16 * (2 * ep) + m;
  const int brow1 = 16 * (2 * ep + 1) + m;

  f32x4 acc0 = {0.f, 0.f, 0.f, 0.f};
  f32x4 acc1 = {0.f, 0.f, 0.f, 0.f};
  float zloc = 0.f;

  const float* krow = kbase + (size_t)(s0 + srow_l) * ROWSTR;
  const float* vrow = vbase + (size_t)(s0 + srow_l) * ROWSTR;
  float4 kA = *(const float4*)(krow + c0);
  float4 kB = *(const float4*)(krow + c1);
  float4 vA = *(const float4*)(vrow + c0);
  float4 vB = *(const float4*)(vrow + c1);

  for (int sub = 0; sub < 8; ++sub) {
    float4 kAn, kBn, vAn, vBn;
    if (sub < 7) {
      const float* krn = kbase + (size_t)(s0 + (sub + 1) * 64 + srow_l) * ROWSTR;
      const float* vrn = vbase + (size_t)(s0 + (sub + 1) * 64 + srow_l) * ROWSTR;
      kAn = *(const float4*)(krn + c0);
      kBn = *(const float4*)(krn + c1);
      vAn = *(const float4*)(vrn + c0);
      vBn = *(const float4*)(vrn + c1);
    }
    float sk[8];
    sk[0] = sigf(kA.x); sk[1] = sigf(kA.y); sk[2] = sigf(kA.z); sk[3] = sigf(kA.w);
    sk[4] = sigf(kB.x); sk[5] = sigf(kB.y); sk[6] = sigf(kB.z); sk[7] = sigf(kB.w);
    float p = (sk[0] + EPSF) * qa.x + (sk[1] + EPSF) * qa.y +
              (sk[2] + EPSF) * qa.z + (sk[3] + EPSF) * qa.w +
              (sk[4] + EPSF) * qb.x + (sk[5] + EPSF) * qb.y +
              (sk[6] + EPSF) * qb.z + (sk[7] + EPSF) * qb.w;
    p = rsum8(p);
    float wgt = __expf(p);
    if (tq == 0) zloc += wgt;
    float vv[8] = {vA.x, vA.y, vA.z, vA.w, vB.x, vB.y, vB.z, vB.w};
#pragma unroll
    for (int i = 0; i < 8; ++i) {
      int d = (i < 4) ? (c0 + i) : (c1 + i - 4);
      unsigned short hh, ll;
      bsplit(sk[i] * wgt, hh, ll);
      kt_hi[d][srow_l] = hh; kt_lo[d][srow_l] = ll;
      bsplit(vv[i], hh, ll);
      vt_hi[d][srow_l] = hh; vt_lo[d][srow_l] = ll;
    }
    __syncthreads();
#pragma unroll
    for (int ks = 0; ks < 2; ++ks) {
      const int sb = ks * 32 + 8 * grp;
      short8v Ah = *(const short8v*)&kt_hi[arow][sb];
      short8v Al = *(const short8v*)&kt_lo[arow][sb];
      short8v B0h = *(const short8v*)&vt_hi[brow0][sb];
      short8v B0l = *(const short8v*)&vt_lo[brow0][sb];
      short8v B1h = *(const short8v*)&vt_hi[brow1][sb];
      short8v B1l = *(const short8v*)&vt_lo[brow1][sb];
      acc0 = __builtin_amdgcn_mfma_f32_16x16x32_bf16(Ah, B0h, acc0, 0, 0, 0);
      acc0 = __builtin_amdgcn_mfma_f32_16x16x32_bf16(Ah, B0l, acc0, 0, 0, 0);
      acc0 = __builtin_amdgcn_mfma_f32_16x16x32_bf16(Al, B0h, acc0, 0, 0, 0);
      acc1 = __builtin_amdgcn_mfma_f32_16x16x32_bf16(Ah, B1h, acc1, 0, 0, 0);
      acc1 = __builtin_amdgcn_mfma_f32_16x16x32_bf16(Ah, B1l, acc1, 0, 0, 0);
      acc1 = __builtin_amdgcn_mfma_f32_16x16x32_bf16(Al, B1h, acc1, 0, 0, 0);
    }
    __syncthreads();
    kA = kAn; kB = kBn; vA = vAn; vB = vBn;
  }

  float* dst = ws + OFF_KVP + (size_t)bid * 4096;
  const int drow = 16 * dblk + 4 * grp;
#pragma unroll
  for (int r = 0; r < 4; ++r) {
    dst[(drow + r) * 64 + brow0] = acc0[r];
    dst[(drow + r) * 64 + brow1] = acc1[r];
  }

  zred[t] = zloc;
  __syncthreads();
  for (int s = 256; s >= 1; s >>= 1) {
    if (t < s) zred[t] += zred[t + s];
    __syncthreads();
  }
  if (t == 0) atomicAdd(&ws[OFF_Z + nh], zred[0]);
}

// ---------------- K4b: reduce 8 partial kv tiles per nh, apply S/Z ----------------
__global__ __launch_bounds__(256) void k_kvred(float* __restrict__ ws) {
  int f = blockIdx.x * 256 + threadIdx.x;  // 0..65535 float4 index
  int nh = f >> 10, off = f & 1023;
  float scale = (float)LL / ws[OFF_Z + nh];
  const float4* src = (const float4*)(ws + OFF_KVP);
  float4 s = make_float4(0.f, 0.f, 0.f, 0.f);
#pragma unroll
  for (int c = 0; c < 8; ++c) {
    float4 x = src[(size_t)((nh * 8 + c) << 10) + off];
    s.x += x.x; s.y += x.y; s.z += x.z; s.w += x.w;
  }
  s.x *= scale; s.y *= scale; s.z *= scale; s.w *= scale;
  ((float4*)(ws + OFF_KV))[f] = s;
}

// ---------------- K5: out = (sig(q) . kv) * nrow * nr ----------------
__global__ __launch_bounds__(256) void k_out(const float* __restrict__ q,
                                             float* __restrict__ out,
                                             const float* __restrict__ ws) {
  int bid = blockIdx.x;  // 2048
  int nh = bid >> 5, chunk = bid & 31;
  int n = nh >> 3, h = nh & 7;
  int t = threadIdx.x, tq = t & 15, g = t >> 4;
  __shared__ float kvs[64][64];
  __shared__ float sq[128][68];   // stride 68: 16B-aligned float4, 2-way banks
  __shared__ float ksv[64], knv[64];
  {
    const float4* kvg = (const float4*)(ws + OFF_KV + (size_t)nh * 4096);
    float4* kvd = (float4*)&kvs[0][0];
#pragma unroll
    for (int i = 0; i < 4; ++i) kvd[i * 256 + t] = kvg[i * 256 + t];
    if (t < 64) {
      ksv[t] = ws[OFF_KSUM + nh * 64 + t] + EPSF;
      knv[t] = ws[OFF_KNSUM + nh * 64 + t] + EPSF;
    }
  }
  __syncthreads();
  const float4 ke = *(const float4*)&ksv[tq * 4];
  const float4 kne = *(const float4*)&knv[tq * 4];
  const float* qbase = q + (size_t)n * NSTR + h * DD + tq * 4;
  float scl[8];
  int l0 = chunk * 128;
#pragma unroll
  for (int rr = 0; rr < 8; ++rr) {
    int row = g + rr * 16;
    const float4 x = *(const float4*)(qbase + (size_t)(l0 + row) * ROWSTR);
    float4 s;
    s.x = sigf(x.x); s.y = sigf(x.y); s.z = sigf(x.z); s.w = sigf(x.w);
    *(float4*)&sq[row][tq * 4] = s;
    float p1 = (s.x + EPSF) * ke.x + (s.y + EPSF) * ke.y +
               (s.z + EPSF) * ke.z + (s.w + EPSF) * ke.w;
    float p2 = (s.x + EPSF) * kne.x + (s.y + EPSF) * kne.y +
               (s.z + EPSF) * kne.z + (s.w + EPSF) * kne.w;
    p1 = rsum16(p1);
    p2 = rsum16(p2);
    scl[rr] = (1.0f / p1) * sigf(p2);  // L/S == 1
  }
  __syncthreads();
  float acc[8][4];
#pragma unroll
  for (int rr = 0; rr < 8; ++rr) {
    acc[rr][0] = 0.f; acc[rr][1] = 0.f; acc[rr][2] = 0.f; acc[rr][3] = 0.f;
  }
  for (int d = 0; d < 64; ++d) {
    const float4 kq = *(const float4*)&kvs[d][tq * 4];
#pragma unroll
    for (int rr = 0; rr < 8; ++rr) {
      float sv = sq[g + rr * 16][d];
      acc[rr][0] += sv * kq.x; acc[rr][1] += sv * kq.y;
      acc[rr][2] += sv * kq.z; acc[rr][3] += sv * kq.w;
    }
  }
  float* obase = out + (size_t)n * NSTR + h * DD + tq * 4;
#pragma unroll
  for (int rr = 0; rr < 8; ++rr) {
    int l = l0 + g + rr * 16;
    float4 o;
    o.x = acc[rr][0] * scl[rr]; o.y = acc[rr][1] * scl[rr];
    o.z = acc[rr][2] * scl[rr]; o.w = acc[rr][3] * scl[rr];
    *(float4*)(obase + (size_t)l * ROWSTR) = o;
  }
}

extern "C" void kernel_launch(void* const* d_in, const int* in_sizes, int n_in,
                              void* d_out, int out_size, void* d_ws, size_t ws_size,
                              hipStream_t stream) {
  const float* q = (const float*)d_in[0];
  const float* k = (const float*)d_in[1];
  const float* v = (const float*)d_in[2];
  float* out = (float*)d_out;
  float* ws = (float*)d_ws;

  // zero accumulators: sums + Z  (kv/kvp fully overwritten each launch)
  hipMemsetAsync(d_ws, 0, (size_t)OFF_KV * sizeof(float), stream);

  hipLaunchKernelGGL(k_sigsum, dim3(1024), dim3(256), 0, stream, q, k, ws);
  hipLaunchKernelGGL(k_stage1, dim3(1024), dim3(256), 0, stream, q, k, ws);
  hipLaunchKernelGGL(k_kv, dim3(512), dim3(512), 0, stream, k, v, ws);
  hipLaunchKernelGGL(k_kvred, dim3(256), dim3(256), 0, stream, ws);
  hipLaunchKernelGGL(k_out, dim3(2048), dim3(256), 0, stream, q, out, ws);
}

// Round 9
// 144.402 us; speedup vs baseline: 1.5328x; 1.0071x over previous
//
#include <hip/hip_runtime.h>

#define EPSF 1e-6f

// dims (fixed for this problem)
#define NB 8
#define LL 4096
#define NHD 8
#define DD 64
#define ROWSTR 512            // H*D
#define NSTR (LL * ROWSTR)    // per-batch stride = 2097152

// workspace float offsets
#define OFF_QSUM 0
#define OFF_KSUM 4096
#define OFF_QNSUM 8192
#define OFF_KNSUM 12288
#define OFF_Z 16384           // 64 floats (atomicAdd target, inside zeroed span)
#define OFF_KV 16448
#define OFF_KVP (OFF_KV + 262144)     // 278592: 64 nh x 8 chunks x 4096 partials
#define KVP_FLOATS (64 * 8 * 4096)    // 2097152

typedef __attribute__((ext_vector_type(8))) short short8v;  // 8 bf16 (4 VGPRs)
typedef __attribute__((ext_vector_type(4))) float f32x4;

__device__ __forceinline__ float sigf(float x) {
  return 1.0f / (1.0f + __expf(-x));
}

__device__ __forceinline__ float rsum16(float p) {
  p += __shfl_xor(p, 1, 16);
  p += __shfl_xor(p, 2, 16);
  p += __shfl_xor(p, 4, 16);
  p += __shfl_xor(p, 8, 16);
  return p;
}

__device__ __forceinline__ float rsum8(float p) {
  p += __shfl_xor(p, 1, 8);
  p += __shfl_xor(p, 2, 8);
  p += __shfl_xor(p, 4, 8);
  return p;
}

// split fp32 -> bf16 hi + bf16 lo (RNE both); hi+lo reconstructs to ~2^-18 rel
__device__ __forceinline__ void bsplit(float x, unsigned short& h, unsigned short& l) {
  unsigned int u = __float_as_uint(x);
  unsigned int hr = (u + 0x7FFFu + ((u >> 16) & 1u)) >> 16;
  h = (unsigned short)hr;
  float hf = __uint_as_float(hr << 16);
  float r = x - hf;
  unsigned int u2 = __float_as_uint(r);
  l = (unsigned short)((u2 + 0x7FFFu + ((u2 >> 16) & 1u)) >> 16);
}

// ---------------- P1: ksum = sum_s sig(k) ----------------
// Block covers 64 full rows (128 KB contiguous); thread owns fixed col quad.
__global__ __launch_bounds__(256) void k_ksum(const float* __restrict__ k,
                                              float* __restrict__ ws) {
  int bid = blockIdx.x;  // 512
  int n = bid >> 6, chunk = bid & 63;
  int t = threadIdx.x;
  const float* base = k + (size_t)n * NSTR + (size_t)chunk * 64 * ROWSTR + t * 4;
  float4 acc = make_float4(0.f, 0.f, 0.f, 0.f);
#pragma unroll 4
  for (int it = 0; it < 32; ++it) {
    const float4 x = *(const float4*)(base + (size_t)it * 1024);
    acc.x += sigf(x.x); acc.y += sigf(x.y); acc.z += sigf(x.z); acc.w += sigf(x.w);
  }
  __shared__ float red[512];
  if (t < 128) {
    red[t * 4 + 0] = acc.x; red[t * 4 + 1] = acc.y;
    red[t * 4 + 2] = acc.z; red[t * 4 + 3] = acc.w;
  }
  __syncthreads();
  if (t >= 128) {
    int c = (t - 128) * 4;
    red[c + 0] += acc.x; red[c + 1] += acc.y;
    red[c + 2] += acc.z; red[c + 3] += acc.w;
  }
  __syncthreads();
  if (t < 128) {
    float* dp = ws + OFF_KSUM + n * 512 + t * 4;
    atomicAdd(dp + 0, red[t * 4 + 0]); atomicAdd(dp + 1, red[t * 4 + 1]);
    atomicAdd(dp + 2, red[t * 4 + 2]); atomicAdd(dp + 3, red[t * 4 + 3]);
  }
}

// ---------------- P2: fused q-pass: qsum AND qn_sum ----------------
// qn_sum[d] = sum_l sig(q)[l][d] / p1[l], p1[l] = sum_d (sig(q)+e)(ksum+e).
__global__ __launch_bounds__(256) void k_qpass(const float* __restrict__ q,
                                               float* __restrict__ ws) {
  int bid = blockIdx.x;  // 512
  int n = bid >> 6, chunk = bid & 63;
  int t = threadIdx.x;
  int col = (t * 4) & 511;  // h = col>>6; 16 lanes per head group
  __shared__ float vec[512];
  if (t < 128) {
    const float* kp = ws + OFF_KSUM + n * 512 + t * 4;
    vec[t * 4 + 0] = kp[0] + EPSF; vec[t * 4 + 1] = kp[1] + EPSF;
    vec[t * 4 + 2] = kp[2] + EPSF; vec[t * 4 + 3] = kp[3] + EPSF;
  }
  __syncthreads();
  const float4 ve = *(const float4*)&vec[col];
  const float* base = q + (size_t)n * NSTR + (size_t)chunk * 64 * ROWSTR + t * 4;
  float4 qacc = make_float4(0.f, 0.f, 0.f, 0.f);   // qsum
  float4 nacc = make_float4(0.f, 0.f, 0.f, 0.f);   // qn_sum
#pragma unroll 4
  for (int it = 0; it < 32; ++it) {
    const float4 x = *(const float4*)(base + (size_t)it * 1024);
    float4 s;
    s.x = sigf(x.x); s.y = sigf(x.y); s.z = sigf(x.z); s.w = sigf(x.w);
    qacc.x += s.x; qacc.y += s.y; qacc.z += s.z; qacc.w += s.w;
    float p = (s.x + EPSF) * ve.x + (s.y + EPSF) * ve.y +
              (s.z + EPSF) * ve.z + (s.w + EPSF) * ve.w;
    p = rsum16(p);  // full row-dot for this head
    float nrm = 1.0f / p;
    nacc.x += s.x * nrm; nacc.y += s.y * nrm; nacc.z += s.z * nrm; nacc.w += s.w * nrm;
  }
  __shared__ float red[512];
  // qsum reduce + atomics
  if (t < 128) {
    red[t * 4 + 0] = qacc.x; red[t * 4 + 1] = qacc.y;
    red[t * 4 + 2] = qacc.z; red[t * 4 + 3] = qacc.w;
  }
  __syncthreads();
  if (t >= 128) {
    int c = (t - 128) * 4;
    red[c + 0] += qacc.x; red[c + 1] += qacc.y;
    red[c + 2] += qacc.z; red[c + 3] += qacc.w;
  }
  __syncthreads();
  if (t < 128) {
    float* dp = ws + OFF_QSUM + n * 512 + t * 4;
    atomicAdd(dp + 0, red[t * 4 + 0]); atomicAdd(dp + 1, red[t * 4 + 1]);
    atomicAdd(dp + 2, red[t * 4 + 2]); atomicAdd(dp + 3, red[t * 4 + 3]);
  }
  __syncthreads();
  // qn_sum reduce + atomics (reuse red)
  if (t < 128) {
    red[t * 4 + 0] = nacc.x; red[t * 4 + 1] = nacc.y;
    red[t * 4 + 2] = nacc.z; red[t * 4 + 3] = nacc.w;
  }
  __syncthreads();
  if (t >= 128) {
    int c = (t - 128) * 4;
    red[c + 0] += nacc.x; red[c + 1] += nacc.y;
    red[c + 2] += nacc.z; red[c + 3] += nacc.w;
  }
  __syncthreads();
  if (t < 128) {
    float* dp = ws + OFF_QNSUM + n * 512 + t * 4;
    atomicAdd(dp + 0, red[t * 4 + 0]); atomicAdd(dp + 1, red[t * 4 + 1]);
    atomicAdd(dp + 2, red[t * 4 + 2]); atomicAdd(dp + 3, red[t * 4 + 3]);
  }
}

// ---------------- P3: kv = khat^T v via MFMA (ncraw + kn_sum fused in) ----------------
__global__ __launch_bounds__(512, 3) void k_kv(const float* __restrict__ k,
                                               const float* __restrict__ v,
                                               float* __restrict__ ws) {
  const int bid = blockIdx.x;  // 512
  const int nh = bid >> 3, chunk = bid & 7;
  const int n = nh >> 3, h = nh & 7;
  const int t = threadIdx.x;

  __shared__ unsigned short kt_hi[64][72], kt_lo[64][72];
  __shared__ unsigned short vt_hi[64][72], vt_lo[64][72];
  __shared__ float zred[512];
  __shared__ float knred[8][64];

  const float* kbase = k + (size_t)n * NSTR + h * DD;
  const float* vbase = v + (size_t)n * NSTR + h * DD;

  const int srow_l = t >> 3;       // 0..63
  const int tq = t & 7;            // 0..7
  const int c0 = tq * 4, c1 = 32 + tq * 4;
  const int s0 = chunk * 512;

  const float* qnp = ws + OFF_QNSUM + nh * 64;
  float4 qa = *(const float4*)(qnp + c0);
  float4 qb = *(const float4*)(qnp + c1);
  qa.x += EPSF; qa.y += EPSF; qa.z += EPSF; qa.w += EPSF;
  qb.x += EPSF; qb.y += EPSF; qb.z += EPSF; qb.w += EPSF;
  const float* qsp = ws + OFF_QSUM + nh * 64;
  float4 sa = *(const float4*)(qsp + c0);
  float4 sb = *(const float4*)(qsp + c1);
  sa.x += EPSF; sa.y += EPSF; sa.z += EPSF; sa.w += EPSF;
  sb.x += EPSF; sb.y += EPSF; sb.z += EPSF; sb.w += EPSF;

  const int w = t >> 6, lane = t & 63;
  const int dblk = w >> 1, ep = w & 1;
  const int m = lane & 15, grp = lane >> 4;
  const int arow = 16 * dblk + m;
  const int brow0 = 16 * (2 * ep) + m;
  const int brow1 = 16 * (2 * ep + 1) + m;

  f32x4 acc0 = {0.f, 0.f, 0.f, 0.f};
  f32x4 acc1 = {0.f, 0.f, 0.f, 0.f};
  float zloc = 0.f;
  float knacc[8];
#pragma unroll
  for (int i = 0; i < 8; ++i) knacc[i] = 0.f;

  const float* krow = kbase + (size_t)(s0 + srow_l) * ROWSTR;
  const float* vrow = vbase + (size_t)(s0 + srow_l) * ROWSTR;
  float4 kA = *(const float4*)(krow + c0);
  float4 kB = *(const float4*)(krow + c1);
  float4 vA = *(const float4*)(vrow + c0);
  float4 vB = *(const float4*)(vrow + c1);

  for (int sub = 0; sub < 8; ++sub) {
    float4 kAn, kBn, vAn, vBn;
    if (sub < 7) {
      const float* krn = kbase + (size_t)(s0 + (sub + 1) * 64 + srow_l) * ROWSTR;
      const float* vrn = vbase + (size_t)(s0 + (sub + 1) * 64 + srow_l) * ROWSTR;
      kAn = *(const float4*)(krn + c0);
      kBn = *(const float4*)(krn + c1);
      vAn = *(const float4*)(vrn + c0);
      vBn = *(const float4*)(vrn + c1);
    }
    float sk[8];
    sk[0] = sigf(kA.x); sk[1] = sigf(kA.y); sk[2] = sigf(kA.z); sk[3] = sigf(kA.w);
    sk[4] = sigf(kB.x); sk[5] = sigf(kB.y); sk[6] = sigf(kB.z); sk[7] = sigf(kB.w);
    // nc dot (vs qn_sum) and col-normalizer dot (vs qsum)
    float p = (sk[0] + EPSF) * qa.x + (sk[1] + EPSF) * qa.y +
              (sk[2] + EPSF) * qa.z + (sk[3] + EPSF) * qa.w +
              (sk[4] + EPSF) * qb.x + (sk[5] + EPSF) * qb.y +
              (sk[6] + EPSF) * qb.z + (sk[7] + EPSF) * qb.w;
    float p2 = (sk[0] + EPSF) * sa.x + (sk[1] + EPSF) * sa.y +
               (sk[2] + EPSF) * sa.z + (sk[3] + EPSF) * sa.w +
               (sk[4] + EPSF) * sb.x + (sk[5] + EPSF) * sb.y +
               (sk[6] + EPSF) * sb.z + (sk[7] + EPSF) * sb.w;
    p = rsum8(p);
    p2 = rsum8(p2);
    float wgt = __expf(p);
    if (tq == 0) zloc += wgt;
    float inv2 = 1.0f / p2;
#pragma unroll
    for (int i = 0; i < 8; ++i) knacc[i] += sk[i] * inv2;
    float vv[8] = {vA.x, vA.y, vA.z, vA.w, vB.x, vB.y, vB.z, vB.w};
#pragma unroll
    for (int i = 0; i < 8; ++i) {
      int d = (i < 4) ? (c0 + i) : (c1 + i - 4);
      unsigned short hh, ll;
      bsplit(sk[i] * wgt, hh, ll);
      kt_hi[d][srow_l] = hh; kt_lo[d][srow_l] = ll;
      bsplit(vv[i], hh, ll);
      vt_hi[d][srow_l] = hh; vt_lo[d][srow_l] = ll;
    }
    __syncthreads();
#pragma unroll
    for (int ks = 0; ks < 2; ++ks) {
      const int sb2 = ks * 32 + 8 * grp;
      short8v Ah = *(const short8v*)&kt_hi[arow][sb2];
      short8v Al = *(const short8v*)&kt_lo[arow][sb2];
      short8v B0h = *(const short8v*)&vt_hi[brow0][sb2];
      short8v B0l = *(const short8v*)&vt_lo[brow0][sb2];
      short8v B1h = *(const short8v*)&vt_hi[brow1][sb2];
      short8v B1l = *(const short8v*)&vt_lo[brow1][sb2];
      acc0 = __builtin_amdgcn_mfma_f32_16x16x32_bf16(Ah, B0h, acc0, 0, 0, 0);
      acc0 = __builtin_amdgcn_mfma_f32_16x16x32_bf16(Ah, B0l, acc0, 0, 0, 0);
      acc0 = __builtin_amdgcn_mfma_f32_16x16x32_bf16(Al, B0h, acc0, 0, 0, 0);
      acc1 = __builtin_amdgcn_mfma_f32_16x16x32_bf16(Ah, B1h, acc1, 0, 0, 0);
      acc1 = __builtin_amdgcn_mfma_f32_16x16x32_bf16(Ah, B1l, acc1, 0, 0, 0);
      acc1 = __builtin_amdgcn_mfma_f32_16x16x32_bf16(Al, B1h, acc1, 0, 0, 0);
    }
    __syncthreads();
    kA = kAn; kB = kBn; vA = vAn; vB = vBn;
  }

  float* dst = ws + OFF_KVP + (size_t)bid * 4096;
  const int drow = 16 * dblk + 4 * grp;
#pragma unroll
  for (int r = 0; r < 4; ++r) {
    dst[(drow + r) * 64 + brow0] = acc0[r];
    dst[(drow + r) * 64 + brow1] = acc1[r];
  }

  // kn_sum reduce: fold lanes sharing tq (xor 8/16/32), then across waves in LDS
#pragma unroll
  for (int i = 0; i < 8; ++i) {
    knacc[i] += __shfl_xor(knacc[i], 8, 64);
    knacc[i] += __shfl_xor(knacc[i], 16, 64);
    knacc[i] += __shfl_xor(knacc[i], 32, 64);
  }
  if (lane < 8) {
#pragma unroll
    for (int i = 0; i < 4; ++i) {
      knred[w][lane * 4 + i] = knacc[i];
      knred[w][32 + lane * 4 + i] = knacc[4 + i];
    }
  }
  // Z reduction
  zred[t] = zloc;
  __syncthreads();
  if (t < 64) {
    float s = 0.f;
#pragma unroll
    for (int ww = 0; ww < 8; ++ww) s += knred[ww][t];
    atomicAdd(&ws[OFF_KNSUM + nh * 64 + t], s);
  }
  for (int s = 256; s >= 1; s >>= 1) {
    if (t < s) zred[t] += zred[t + s];
    __syncthreads();
  }
  if (t == 0) atomicAdd(&ws[OFF_Z + nh], zred[0]);
}

// ---------------- P4: reduce 8 partial kv tiles per nh, apply S/Z ----------------
__global__ __launch_bounds__(256) void k_kvred(float* __restrict__ ws) {
  int f = blockIdx.x * 256 + threadIdx.x;  // 0..65535 float4 index
  int nh = f >> 10, off = f & 1023;
  float scale = (float)LL / ws[OFF_Z + nh];
  const float4* src = (const float4*)(ws + OFF_KVP);
  float4 s = make_float4(0.f, 0.f, 0.f, 0.f);
#pragma unroll
  for (int c = 0; c < 8; ++c) {
    float4 x = src[(size_t)((nh * 8 + c) << 10) + off];
    s.x += x.x; s.y += x.y; s.z += x.z; s.w += x.w;
  }
  s.x *= scale; s.y *= scale; s.z *= scale; s.w *= scale;
  ((float4*)(ws + OFF_KV))[f] = s;
}

// ---------------- P5: out = (sig(q) . kv) * nrow * nr ----------------
__global__ __launch_bounds__(256) void k_out(const float* __restrict__ q,
                                             float* __restrict__ out,
                                             const float* __restrict__ ws) {
  int bid = blockIdx.x;  // 2048
  int nh = bid >> 5, chunk = bid & 31;
  int n = nh >> 3, h = nh & 7;
  int t = threadIdx.x, tq = t & 15, g = t >> 4;
  __shared__ float kvs[64][64];
  __shared__ float sq[128][68];   // stride 68: 16B-aligned float4, 2-way banks
  __shared__ float ksv[64], knv[64];
  {
    const float4* kvg = (const float4*)(ws + OFF_KV + (size_t)nh * 4096);
    float4* kvd = (float4*)&kvs[0][0];
#pragma unroll
    for (int i = 0; i < 4; ++i) kvd[i * 256 + t] = kvg[i * 256 + t];
    if (t < 64) {
      ksv[t] = ws[OFF_KSUM + nh * 64 + t] + EPSF;
      knv[t] = ws[OFF_KNSUM + nh * 64 + t] + EPSF;
    }
  }
  __syncthreads();
  const float4 ke = *(const float4*)&ksv[tq * 4];
  const float4 kne = *(const float4*)&knv[tq * 4];
  const float* qbase = q + (size_t)n * NSTR + h * DD + tq * 4;
  float scl[8];
  int l0 = chunk * 128;
#pragma unroll
  for (int rr = 0; rr < 8; ++rr) {
    int row = g + rr * 16;
    const float4 x = *(const float4*)(qbase + (size_t)(l0 + row) * ROWSTR);
    float4 s;
    s.x = sigf(x.x); s.y = sigf(x.y); s.z = sigf(x.z); s.w = sigf(x.w);
    *(float4*)&sq[row][tq * 4] = s;
    float p1 = (s.x + EPSF) * ke.x + (s.y + EPSF) * ke.y +
               (s.z + EPSF) * ke.z + (s.w + EPSF) * ke.w;
    float p2 = (s.x + EPSF) * kne.x + (s.y + EPSF) * kne.y +
               (s.z + EPSF) * kne.z + (s.w + EPSF) * kne.w;
    p1 = rsum16(p1);
    p2 = rsum16(p2);
    scl[rr] = (1.0f / p1) * sigf(p2);  // L/S == 1
  }
  __syncthreads();
  float acc[8][4];
#pragma unroll
  for (int rr = 0; rr < 8; ++rr) {
    acc[rr][0] = 0.f; acc[rr][1] = 0.f; acc[rr][2] = 0.f; acc[rr][3] = 0.f;
  }
  for (int d = 0; d < 64; ++d) {
    const float4 kq = *(const float4*)&kvs[d][tq * 4];
#pragma unroll
    for (int rr = 0; rr < 8; ++rr) {
      float sv = sq[g + rr * 16][d];
      acc[rr][0] += sv * kq.x; acc[rr][1] += sv * kq.y;
      acc[rr][2] += sv * kq.z; acc[rr][3] += sv * kq.w;
    }
  }
  float* obase = out + (size_t)n * NSTR + h * DD + tq * 4;
#pragma unroll
  for (int rr = 0; rr < 8; ++rr) {
    int l = l0 + g + rr * 16;
    float4 o;
    o.x = acc[rr][0] * scl[rr]; o.y = acc[rr][1] * scl[rr];
    o.z = acc[rr][2] * scl[rr]; o.w = acc[rr][3] * scl[rr];
    *(float4*)(obase + (size_t)l * ROWSTR) = o;
  }
}

extern "C" void kernel_launch(void* const* d_in, const int* in_sizes, int n_in,
                              void* d_out, int out_size, void* d_ws, size_t ws_size,
                              hipStream_t stream) {
  const float* q = (const float*)d_in[0];
  const float* k = (const float*)d_in[1];
  const float* v = (const float*)d_in[2];
  float* out = (float*)d_out;
  float* ws = (float*)d_ws;

  // zero accumulators: sums + Z  (kv/kvp fully overwritten each launch)
  hipMemsetAsync(d_ws, 0, (size_t)OFF_KV * sizeof(float), stream);

  hipLaunchKernelGGL(k_ksum, dim3(512), dim3(256), 0, stream, k, ws);
  hipLaunchKernelGGL(k_qpass, dim3(512), dim3(256), 0, stream, q, ws);
  hipLaunchKernelGGL(k_kv, dim3(512), dim3(512), 0, stream, k, v, ws);
  hipLaunchKernelGGL(k_kvred, dim3(256), dim3(256), 0, stream, ws);
  hipLaunchKernelGGL(k_out, dim3(2048), dim3(256), 0, stream, q, out, ws);
}

// Round 10
// 131.301 us; speedup vs baseline: 1.6857x; 1.0998x over previous
//
#include <hip/hip_runtime.h>

#define EPSF 1e-6f

// dims (fixed for this problem)
#define NB 8
#define LL 4096
#define NHD 8
#define DD 64
#define ROWSTR 512            // H*D
#define NSTR (LL * ROWSTR)    // per-batch stride = 2097152

// workspace float offsets
#define OFF_QSUM 0
#define OFF_KSUM 4096
#define OFF_QNSUM 8192
#define OFF_KNSUM 12288
#define OFF_Z 16384           // 64 floats (atomicAdd target, inside zeroed span)
#define OFF_KV 16448          // now: 64 nh x 4096 ushort bf16 kv^T (512 KB)
#define OFF_KVP (OFF_KV + 262144)     // 278592: 64 nh x 8 chunks x 4096 partials
#define KVP_FLOATS (64 * 8 * 4096)    // 2097152

typedef __attribute__((ext_vector_type(8))) short short8v;  // 8 bf16 (4 VGPRs)
typedef __attribute__((ext_vector_type(4))) float f32x4;

__device__ __forceinline__ float sigf(float x) {
  return 1.0f / (1.0f + __expf(-x));
}

__device__ __forceinline__ float rsum16(float p) {
  p += __shfl_xor(p, 1, 16);
  p += __shfl_xor(p, 2, 16);
  p += __shfl_xor(p, 4, 16);
  p += __shfl_xor(p, 8, 16);
  return p;
}

__device__ __forceinline__ float rsum8(float p) {
  p += __shfl_xor(p, 1, 8);
  p += __shfl_xor(p, 2, 8);
  p += __shfl_xor(p, 4, 8);
  return p;
}

// split fp32 -> bf16 hi + bf16 lo (RNE both); hi+lo reconstructs to ~2^-18 rel
__device__ __forceinline__ void bsplit(float x, unsigned short& h, unsigned short& l) {
  unsigned int u = __float_as_uint(x);
  unsigned int hr = (u + 0x7FFFu + ((u >> 16) & 1u)) >> 16;
  h = (unsigned short)hr;
  float hf = __uint_as_float(hr << 16);
  float r = x - hf;
  unsigned int u2 = __float_as_uint(r);
  l = (unsigned short)((u2 + 0x7FFFu + ((u2 >> 16) & 1u)) >> 16);
}

__device__ __forceinline__ unsigned short b16rne(float x) {
  unsigned int u = __float_as_uint(x);
  return (unsigned short)((u + 0x7FFFu + ((u >> 16) & 1u)) >> 16);
}

__device__ __forceinline__ unsigned int pack2(float a, float b) {
  return (unsigned int)b16rne(a) | ((unsigned int)b16rne(b) << 16);
}

// ---------------- P1: ksum = sum_s sig(k) ----------------
__global__ __launch_bounds__(256) void k_ksum(const float* __restrict__ k,
                                              float* __restrict__ ws) {
  int bid = blockIdx.x;  // 512
  int n = bid >> 6, chunk = bid & 63;
  int t = threadIdx.x;
  const float* base = k + (size_t)n * NSTR + (size_t)chunk * 64 * ROWSTR + t * 4;
  float4 acc = make_float4(0.f, 0.f, 0.f, 0.f);
#pragma unroll 4
  for (int it = 0; it < 32; ++it) {
    const float4 x = *(const float4*)(base + (size_t)it * 1024);
    acc.x += sigf(x.x); acc.y += sigf(x.y); acc.z += sigf(x.z); acc.w += sigf(x.w);
  }
  __shared__ float red[512];
  if (t < 128) {
    red[t * 4 + 0] = acc.x; red[t * 4 + 1] = acc.y;
    red[t * 4 + 2] = acc.z; red[t * 4 + 3] = acc.w;
  }
  __syncthreads();
  if (t >= 128) {
    int c = (t - 128) * 4;
    red[c + 0] += acc.x; red[c + 1] += acc.y;
    red[c + 2] += acc.z; red[c + 3] += acc.w;
  }
  __syncthreads();
  if (t < 128) {
    float* dp = ws + OFF_KSUM + n * 512 + t * 4;
    atomicAdd(dp + 0, red[t * 4 + 0]); atomicAdd(dp + 1, red[t * 4 + 1]);
    atomicAdd(dp + 2, red[t * 4 + 2]); atomicAdd(dp + 3, red[t * 4 + 3]);
  }
}

// ---------------- P2: fused q-pass: qsum AND qn_sum ----------------
__global__ __launch_bounds__(256) void k_qpass(const float* __restrict__ q,
                                               float* __restrict__ ws) {
  int bid = blockIdx.x;  // 512
  int n = bid >> 6, chunk = bid & 63;
  int t = threadIdx.x;
  int col = (t * 4) & 511;
  __shared__ float vec[512];
  if (t < 128) {
    const float* kp = ws + OFF_KSUM + n * 512 + t * 4;
    vec[t * 4 + 0] = kp[0] + EPSF; vec[t * 4 + 1] = kp[1] + EPSF;
    vec[t * 4 + 2] = kp[2] + EPSF; vec[t * 4 + 3] = kp[3] + EPSF;
  }
  __syncthreads();
  const float4 ve = *(const float4*)&vec[col];
  const float* base = q + (size_t)n * NSTR + (size_t)chunk * 64 * ROWSTR + t * 4;
  float4 qacc = make_float4(0.f, 0.f, 0.f, 0.f);
  float4 nacc = make_float4(0.f, 0.f, 0.f, 0.f);
#pragma unroll 4
  for (int it = 0; it < 32; ++it) {
    const float4 x = *(const float4*)(base + (size_t)it * 1024);
    float4 s;
    s.x = sigf(x.x); s.y = sigf(x.y); s.z = sigf(x.z); s.w = sigf(x.w);
    qacc.x += s.x; qacc.y += s.y; qacc.z += s.z; qacc.w += s.w;
    float p = (s.x + EPSF) * ve.x + (s.y + EPSF) * ve.y +
              (s.z + EPSF) * ve.z + (s.w + EPSF) * ve.w;
    p = rsum16(p);
    float nrm = 1.0f / p;
    nacc.x += s.x * nrm; nacc.y += s.y * nrm; nacc.z += s.z * nrm; nacc.w += s.w * nrm;
  }
  __shared__ float red[512];
  if (t < 128) {
    red[t * 4 + 0] = qacc.x; red[t * 4 + 1] = qacc.y;
    red[t * 4 + 2] = qacc.z; red[t * 4 + 3] = qacc.w;
  }
  __syncthreads();
  if (t >= 128) {
    int c = (t - 128) * 4;
    red[c + 0] += qacc.x; red[c + 1] += qacc.y;
    red[c + 2] += qacc.z; red[c + 3] += qacc.w;
  }
  __syncthreads();
  if (t < 128) {
    float* dp = ws + OFF_QSUM + n * 512 + t * 4;
    atomicAdd(dp + 0, red[t * 4 + 0]); atomicAdd(dp + 1, red[t * 4 + 1]);
    atomicAdd(dp + 2, red[t * 4 + 2]); atomicAdd(dp + 3, red[t * 4 + 3]);
  }
  __syncthreads();
  if (t < 128) {
    red[t * 4 + 0] = nacc.x; red[t * 4 + 1] = nacc.y;
    red[t * 4 + 2] = nacc.z; red[t * 4 + 3] = nacc.w;
  }
  __syncthreads();
  if (t >= 128) {
    int c = (t - 128) * 4;
    red[c + 0] += nacc.x; red[c + 1] += nacc.y;
    red[c + 2] += nacc.z; red[c + 3] += nacc.w;
  }
  __syncthreads();
  if (t < 128) {
    float* dp = ws + OFF_QNSUM + n * 512 + t * 4;
    atomicAdd(dp + 0, red[t * 4 + 0]); atomicAdd(dp + 1, red[t * 4 + 1]);
    atomicAdd(dp + 2, red[t * 4 + 2]); atomicAdd(dp + 3, red[t * 4 + 3]);
  }
}

// ---------------- P3: kv = khat^T v via MFMA (ncraw + kn_sum fused in) ----------------
__global__ __launch_bounds__(512, 3) void k_kv(const float* __restrict__ k,
                                               const float* __restrict__ v,
                                               float* __restrict__ ws) {
  const int bid = blockIdx.x;  // 512
  const int nh = bid >> 3, chunk = bid & 7;
  const int n = nh >> 3, h = nh & 7;
  const int t = threadIdx.x;

  __shared__ unsigned short kt_hi[64][72], kt_lo[64][72];
  __shared__ unsigned short vt_hi[64][72], vt_lo[64][72];
  __shared__ float zred[512];
  __shared__ float knred[8][64];

  const float* kbase = k + (size_t)n * NSTR + h * DD;
  const float* vbase = v + (size_t)n * NSTR + h * DD;

  const int srow_l = t >> 3;
  const int tq = t & 7;
  const int c0 = tq * 4, c1 = 32 + tq * 4;
  const int s0 = chunk * 512;

  const float* qnp = ws + OFF_QNSUM + nh * 64;
  float4 qa = *(const float4*)(qnp + c0);
  float4 qb = *(const float4*)(qnp + c1);
  qa.x += EPSF; qa.y += EPSF; qa.z += EPSF; qa.w += EPSF;
  qb.x += EPSF; qb.y += EPSF; qb.z += EPSF; qb.w += EPSF;
  const float* qsp = ws + OFF_QSUM + nh * 64;
  float4 sa = *(const float4*)(qsp + c0);
  float4 sb = *(const float4*)(qsp + c1);
  sa.x += EPSF; sa.y += EPSF; sa.z += EPSF; sa.w += EPSF;
  sb.x += EPSF; sb.y += EPSF; sb.z += EPSF; sb.w += EPSF;

  const int w = t >> 6, lane = t & 63;
  const int dblk = w >> 1, ep = w & 1;
  const int m = lane & 15, grp = lane >> 4;
  const int arow = 16 * dblk + m;
  const int brow0 = 16 * (2 * ep) + m;
  const int brow1 = 16 * (2 * ep + 1) + m;

  f32x4 acc0 = {0.f, 0.f, 0.f, 0.f};
  f32x4 acc1 = {0.f, 0.f, 0.f, 0.f};
  float zloc = 0.f;
  float knacc[8];
#pragma unroll
  for (int i = 0; i < 8; ++i) knacc[i] = 0.f;

  const float* krow = kbase + (size_t)(s0 + srow_l) * ROWSTR;
  const float* vrow = vbase + (size_t)(s0 + srow_l) * ROWSTR;
  float4 kA = *(const float4*)(krow + c0);
  float4 kB = *(const float4*)(krow + c1);
  float4 vA = *(const float4*)(vrow + c0);
  float4 vB = *(const float4*)(vrow + c1);

  for (int sub = 0; sub < 8; ++sub) {
    float4 kAn, kBn, vAn, vBn;
    if (sub < 7) {
      const float* krn = kbase + (size_t)(s0 + (sub + 1) * 64 + srow_l) * ROWSTR;
      const float* vrn = vbase + (size_t)(s0 + (sub + 1) * 64 + srow_l) * ROWSTR;
      kAn = *(const float4*)(krn + c0);
      kBn = *(const float4*)(krn + c1);
      vAn = *(const float4*)(vrn + c0);
      vBn = *(const float4*)(vrn + c1);
    }
    float sk[8];
    sk[0] = sigf(kA.x); sk[1] = sigf(kA.y); sk[2] = sigf(kA.z); sk[3] = sigf(kA.w);
    sk[4] = sigf(kB.x); sk[5] = sigf(kB.y); sk[6] = sigf(kB.z); sk[7] = sigf(kB.w);
    float p = (sk[0] + EPSF) * qa.x + (sk[1] + EPSF) * qa.y +
              (sk[2] + EPSF) * qa.z + (sk[3] + EPSF) * qa.w +
              (sk[4] + EPSF) * qb.x + (sk[5] + EPSF) * qb.y +
              (sk[6] + EPSF) * qb.z + (sk[7] + EPSF) * qb.w;
    float p2 = (sk[0] + EPSF) * sa.x + (sk[1] + EPSF) * sa.y +
               (sk[2] + EPSF) * sa.z + (sk[3] + EPSF) * sa.w +
               (sk[4] + EPSF) * sb.x + (sk[5] + EPSF) * sb.y +
               (sk[6] + EPSF) * sb.z + (sk[7] + EPSF) * sb.w;
    p = rsum8(p);
    p2 = rsum8(p2);
    float wgt = __expf(p);
    if (tq == 0) zloc += wgt;
    float inv2 = 1.0f / p2;
#pragma unroll
    for (int i = 0; i < 8; ++i) knacc[i] += sk[i] * inv2;
    float vv[8] = {vA.x, vA.y, vA.z, vA.w, vB.x, vB.y, vB.z, vB.w};
#pragma unroll
    for (int i = 0; i < 8; ++i) {
      int d = (i < 4) ? (c0 + i) : (c1 + i - 4);
      unsigned short hh, ll;
      bsplit(sk[i] * wgt, hh, ll);
      kt_hi[d][srow_l] = hh; kt_lo[d][srow_l] = ll;
      bsplit(vv[i], hh, ll);
      vt_hi[d][srow_l] = hh; vt_lo[d][srow_l] = ll;
    }
    __syncthreads();
#pragma unroll
    for (int ks = 0; ks < 2; ++ks) {
      const int sb2 = ks * 32 + 8 * grp;
      short8v Ah = *(const short8v*)&kt_hi[arow][sb2];
      short8v Al = *(const short8v*)&kt_lo[arow][sb2];
      short8v B0h = *(const short8v*)&vt_hi[brow0][sb2];
      short8v B0l = *(const short8v*)&vt_lo[brow0][sb2];
      short8v B1h = *(const short8v*)&vt_hi[brow1][sb2];
      short8v B1l = *(const short8v*)&vt_lo[brow1][sb2];
      acc0 = __builtin_amdgcn_mfma_f32_16x16x32_bf16(Ah, B0h, acc0, 0, 0, 0);
      acc0 = __builtin_amdgcn_mfma_f32_16x16x32_bf16(Ah, B0l, acc0, 0, 0, 0);
      acc0 = __builtin_amdgcn_mfma_f32_16x16x32_bf16(Al, B0h, acc0, 0, 0, 0);
      acc1 = __builtin_amdgcn_mfma_f32_16x16x32_bf16(Ah, B1h, acc1, 0, 0, 0);
      acc1 = __builtin_amdgcn_mfma_f32_16x16x32_bf16(Ah, B1l, acc1, 0, 0, 0);
      acc1 = __builtin_amdgcn_mfma_f32_16x16x32_bf16(Al, B1h, acc1, 0, 0, 0);
    }
    __syncthreads();
    kA = kAn; kB = kBn; vA = vAn; vB = vBn;
  }

  float* dst = ws + OFF_KVP + (size_t)bid * 4096;
  const int drow = 16 * dblk + 4 * grp;
#pragma unroll
  for (int r = 0; r < 4; ++r) {
    dst[(drow + r) * 64 + brow0] = acc0[r];
    dst[(drow + r) * 64 + brow1] = acc1[r];
  }

#pragma unroll
  for (int i = 0; i < 8; ++i) {
    knacc[i] += __shfl_xor(knacc[i], 8, 64);
    knacc[i] += __shfl_xor(knacc[i], 16, 64);
    knacc[i] += __shfl_xor(knacc[i], 32, 64);
  }
  if (lane < 8) {
#pragma unroll
    for (int i = 0; i < 4; ++i) {
      knred[w][lane * 4 + i] = knacc[i];
      knred[w][32 + lane * 4 + i] = knacc[4 + i];
    }
  }
  zred[t] = zloc;
  __syncthreads();
  if (t < 64) {
    float s = 0.f;
#pragma unroll
    for (int ww = 0; ww < 8; ++ww) s += knred[ww][t];
    atomicAdd(&ws[OFF_KNSUM + nh * 64 + t], s);
  }
  for (int s = 256; s >= 1; s >>= 1) {
    if (t < s) zred[t] += zred[t + s];
    __syncthreads();
  }
  if (t == 0) atomicAdd(&ws[OFF_Z + nh], zred[0]);
}

// ---------------- P4: reduce partials, apply S/Z, transpose, emit bf16 kv^T ----------------
__global__ __launch_bounds__(256) void k_kvred(float* __restrict__ ws) {
  int nh = blockIdx.x;  // 64
  int t = threadIdx.x;
  float scale = (float)LL / ws[OFF_Z + nh];
  __shared__ float lds[64][69];
  const float4* src = (const float4*)(ws + OFF_KVP);
#pragma unroll
  for (int i = 0; i < 4; ++i) {
    int off = i * 256 + t;  // float4 index 0..1023 within nh ([d][e] layout)
    float4 s = make_float4(0.f, 0.f, 0.f, 0.f);
#pragma unroll
    for (int c = 0; c < 8; ++c) {
      float4 x = src[(size_t)((nh * 8 + c) << 10) + off];
      s.x += x.x; s.y += x.y; s.z += x.z; s.w += x.w;
    }
    int d = off >> 4, e0 = (off & 15) * 4;
    lds[d][e0 + 0] = s.x * scale; lds[d][e0 + 1] = s.y * scale;
    lds[d][e0 + 2] = s.z * scale; lds[d][e0 + 3] = s.w * scale;
  }
  __syncthreads();
  // transpose + bf16 pack: thread -> row e = t>>2, cols d0 = (t&3)*16
  int e = t >> 2, d0 = (t & 3) * 16;
  unsigned int words[8];
#pragma unroll
  for (int j = 0; j < 8; ++j)
    words[j] = pack2(lds[d0 + 2 * j][e], lds[d0 + 2 * j + 1][e]);
  unsigned int* dstp = (unsigned int*)((unsigned short*)(ws + OFF_KV) + (size_t)nh * 4096 + e * 64 + d0);
#pragma unroll
  for (int j = 0; j < 8; ++j) dstp[j] = words[j];
}

// ---------------- P5: out = (sig(q) . kv) * scl via MFMA ----------------
__global__ __launch_bounds__(256) void k_out(const float* __restrict__ q,
                                             float* __restrict__ out,
                                             const float* __restrict__ ws) {
  int bid = blockIdx.x;  // 2048
  int nh = bid >> 5, chunk = bid & 31;
  int n = nh >> 3, h = nh & 7;
  int t = threadIdx.x, tq = t & 15, g = t >> 4;
  __shared__ unsigned short sqb[128][72];   // bf16 sig(q), rows l
  __shared__ unsigned short kvb[64][72];    // bf16 kv^T, rows e
  __shared__ float scl[128];
  __shared__ float ksv[64], knv[64];
  if (t < 64) {
    ksv[t] = ws[OFF_KSUM + nh * 64 + t] + EPSF;
    knv[t] = ws[OFF_KNSUM + nh * 64 + t] + EPSF;
  }
  {
    int r0 = t >> 2, c0 = (t & 3) * 16;
    const short8v* gsrc = (const short8v*)((const unsigned short*)(ws + OFF_KV) +
                                           (size_t)nh * 4096 + r0 * 64 + c0);
    short8v a = gsrc[0], b = gsrc[1];
    *(short8v*)&kvb[r0][c0] = a;
    *(short8v*)&kvb[r0][c0 + 8] = b;
  }
  __syncthreads();
  const float4 ke = *(const float4*)&ksv[tq * 4];
  const float4 kne = *(const float4*)&knv[tq * 4];
  const float* qbase = q + (size_t)n * NSTR + h * DD + tq * 4;
  int l0 = chunk * 128;
#pragma unroll
  for (int rr = 0; rr < 8; ++rr) {
    int row = g + rr * 16;
    const float4 x = *(const float4*)(qbase + (size_t)(l0 + row) * ROWSTR);
    float4 s;
    s.x = sigf(x.x); s.y = sigf(x.y); s.z = sigf(x.z); s.w = sigf(x.w);
    *(unsigned int*)&sqb[row][tq * 4] = pack2(s.x, s.y);
    *(unsigned int*)&sqb[row][tq * 4 + 2] = pack2(s.z, s.w);
    float p1 = (s.x + EPSF) * ke.x + (s.y + EPSF) * ke.y +
               (s.z + EPSF) * ke.z + (s.w + EPSF) * ke.w;
    float p2 = (s.x + EPSF) * kne.x + (s.y + EPSF) * kne.y +
               (s.z + EPSF) * kne.z + (s.w + EPSF) * kne.w;
    p1 = rsum16(p1);
    p2 = rsum16(p2);
    if (tq == 0) scl[row] = (1.0f / p1) * sigf(p2);  // L/S == 1
  }
  __syncthreads();
  // MFMA: wave w handles M-tiles {2w, 2w+1}; 4 N-tiles; K=64 in 2 steps
  int w = t >> 6, lane = t & 63;
  int m = lane & 15, grp = lane >> 4;
  f32x4 a00 = {0,0,0,0}, a01 = {0,0,0,0}, a02 = {0,0,0,0}, a03 = {0,0,0,0};
  f32x4 a10 = {0,0,0,0}, a11 = {0,0,0,0}, a12 = {0,0,0,0}, a13 = {0,0,0,0};
#pragma unroll
  for (int ks = 0; ks < 2; ++ks) {
    const int sb = ks * 32 + 8 * grp;
    short8v A0 = *(const short8v*)&sqb[(2 * w + 0) * 16 + m][sb];
    short8v A1 = *(const short8v*)&sqb[(2 * w + 1) * 16 + m][sb];
    short8v B0 = *(const short8v*)&kvb[0 * 16 + m][sb];
    short8v B1 = *(const short8v*)&kvb[1 * 16 + m][sb];
    short8v B2 = *(const short8v*)&kvb[2 * 16 + m][sb];
    short8v B3 = *(const short8v*)&kvb[3 * 16 + m][sb];
    a00 = __builtin_amdgcn_mfma_f32_16x16x32_bf16(A0, B0, a00, 0, 0, 0);
    a01 = __builtin_amdgcn_mfma_f32_16x16x32_bf16(A0, B1, a01, 0, 0, 0);
    a02 = __builtin_amdgcn_mfma_f32_16x16x32_bf16(A0, B2, a02, 0, 0, 0);
    a03 = __builtin_amdgcn_mfma_f32_16x16x32_bf16(A0, B3, a03, 0, 0, 0);
    a10 = __builtin_amdgcn_mfma_f32_16x16x32_bf16(A1, B0, a10, 0, 0, 0);
    a11 = __builtin_amdgcn_mfma_f32_16x16x32_bf16(A1, B1, a11, 0, 0, 0);
    a12 = __builtin_amdgcn_mfma_f32_16x16x32_bf16(A1, B2, a12, 0, 0, 0);
    a13 = __builtin_amdgcn_mfma_f32_16x16x32_bf16(A1, B3, a13, 0, 0, 0);
  }
  float* obase = out + (size_t)n * NSTR + h * DD;
#pragma unroll
  for (int mt = 0; mt < 2; ++mt) {
    int lrow = (2 * w + mt) * 16 + 4 * grp;
#pragma unroll
    for (int r = 0; r < 4; ++r) {
      float sc = scl[lrow + r];
      float* orow = obase + (size_t)(l0 + lrow + r) * ROWSTR;
      if (mt == 0) {
        orow[0 * 16 + m] = a00[r] * sc; orow[1 * 16 + m] = a01[r] * sc;
        orow[2 * 16 + m] = a02[r] * sc; orow[3 * 16 + m] = a03[r] * sc;
      } else {
        orow[0 * 16 + m] = a10[r] * sc; orow[1 * 16 + m] = a11[r] * sc;
        orow[2 * 16 + m] = a12[r] * sc; orow[3 * 16 + m] = a13[r] * sc;
      }
    }
  }
}

extern "C" void kernel_launch(void* const* d_in, const int* in_sizes, int n_in,
                              void* d_out, int out_size, void* d_ws, size_t ws_size,
                              hipStream_t stream) {
  const float* q = (const float*)d_in[0];
  const float* k = (const float*)d_in[1];
  const float* v = (const float*)d_in[2];
  float* out = (float*)d_out;
  float* ws = (float*)d_ws;

  // zero accumulators: sums + Z  (kv^T/kvp fully overwritten each launch)
  hipMemsetAsync(d_ws, 0, (size_t)OFF_KV * sizeof(float), stream);

  hipLaunchKernelGGL(k_ksum, dim3(512), dim3(256), 0, stream, k, ws);
  hipLaunchKernelGGL(k_qpass, dim3(512), dim3(256), 0, stream, q, ws);
  hipLaunchKernelGGL(k_kv, dim3(512), dim3(512), 0, stream, k, v, ws);
  hipLaunchKernelGGL(k_kvred, dim3(64), dim3(256), 0, stream, ws);
  hipLaunchKernelGGL(k_out, dim3(2048), dim3(256), 0, stream, q, out, ws);
}